// Round 1
// baseline (1194.431 us; speedup 1.0000x reference)
//
#include <hip/hip_runtime.h>

// Problem constants (fixed by setup_inputs)
constexpr int Bn = 65536;   // rows of x
constexpr int Cn = 4096;    // codebook entries
constexpr int Dn = 128;     // feature dim
constexpr int BM = 64;      // rows per block
constexpr int BN = 64;      // codes per N-tile

// ---------------------------------------------------------------------------
// Kernel 1: code norms (fp64 accumulate -> fp32), also zeroes the loss slot.
// ---------------------------------------------------------------------------
__global__ void cnorm_kernel(const float* __restrict__ codes,
                             float* __restrict__ cnorm,
                             float* __restrict__ loss) {
  int n = blockIdx.x * blockDim.x + threadIdx.x;
  if (blockIdx.x == 0 && threadIdx.x == 0) *loss = 0.f;
  if (n >= Cn) return;
  const float4* p = (const float4*)(codes + (size_t)n * Dn);
  double s = 0.0;
#pragma unroll
  for (int i = 0; i < Dn / 4; ++i) {
    float4 v = p[i];
    s += (double)v.x * v.x + (double)v.y * v.y + (double)v.z * v.z +
         (double)v.w * v.w;
  }
  cnorm[n] = (float)s;
}

// ---------------------------------------------------------------------------
// Kernel 2: fused fp32 GEMM + streaming argmin.
// key[m][n] = cnorm[n] - 2*dot(x[m], c[n]); argmin over n matches argmin of
// the reference distances (monotone transform, xnorm[m] constant per row).
// Block: 256 threads, 64 rows, iterate 64-code tiles over all 4096 codes.
// LDS: As[k][m] persistent (x tile), Bs[k][n] staged per K-half.
// ---------------------------------------------------------------------------
__launch_bounds__(256, 2)
__global__ void argmin_kernel(const float* __restrict__ x,
                              const float* __restrict__ codes,
                              const float* __restrict__ cnorm,
                              float* __restrict__ idxf) {
  __shared__ __align__(16) float As[Dn][68];  // [k][m], 34816 B (pad 68: 16B-aligned rows)
  __shared__ __align__(16) float Bs[64][68];  // [k-half][n], 17408 B
  __shared__ float redv[BM][17];
  __shared__ int   redi[BM][17];

  const int t = threadIdx.x;
  const int row0 = blockIdx.x * BM;

  // Stage x tile transposed: As[k][m]. Coalesced float4 global reads.
  {
    const float* xp = x + (size_t)row0 * Dn;
#pragma unroll
    for (int it = 0; it < 8; ++it) {
      int m = (t >> 5) + (it << 3);
      int k4 = (t & 31) << 2;
      float4 v = *(const float4*)(xp + (size_t)m * Dn + k4);
      As[k4 + 0][m] = v.x;
      As[k4 + 1][m] = v.y;
      As[k4 + 2][m] = v.z;
      As[k4 + 3][m] = v.w;
    }
  }

  const int m0 = (t & 15) << 2;  // 4 rows owned by this thread
  const int n0 = (t >> 4) << 2;  // 4 cols (within tile) owned by this thread

  float minv[4] = {3.4e38f, 3.4e38f, 3.4e38f, 3.4e38f};
  int   mini[4] = {0, 0, 0, 0};

  for (int nt = 0; nt < Cn / BN; ++nt) {
    const int nbase = nt * BN;
    float acc[4][4];
#pragma unroll
    for (int i = 0; i < 4; ++i)
#pragma unroll
      for (int j = 0; j < 4; ++j) acc[i][j] = 0.f;

#pragma unroll
    for (int kh = 0; kh < 2; ++kh) {
      __syncthreads();  // protect Bs from previous K-loop readers
      // Stage codes half-tile transposed: Bs[k][n], k in [0,64)
#pragma unroll
      for (int it = 0; it < 4; ++it) {
        int n = (t >> 4) + (it << 4);
        int k4 = (t & 15) << 2;
        float4 v = *(const float4*)(codes + (size_t)(nbase + n) * Dn +
                                    (kh << 6) + k4);
        Bs[k4 + 0][n] = v.x;
        Bs[k4 + 1][n] = v.y;
        Bs[k4 + 2][n] = v.z;
        Bs[k4 + 3][n] = v.w;
      }
      __syncthreads();
      const int kb = kh << 6;
#pragma unroll 8
      for (int k = 0; k < 64; ++k) {
        float4 av = *(const float4*)&As[kb + k][m0];
        float4 bv = *(const float4*)&Bs[k][n0];
        float a[4] = {av.x, av.y, av.z, av.w};
        float b[4] = {bv.x, bv.y, bv.z, bv.w};
#pragma unroll
        for (int i = 0; i < 4; ++i)
#pragma unroll
          for (int j = 0; j < 4; ++j)
            acc[i][j] = fmaf(a[i], b[j], acc[i][j]);
      }
    }

    // Epilogue: running argmin. Ascending n + strict '<' = first-index ties,
    // matching np.argmin.
#pragma unroll
    for (int j = 0; j < 4; ++j) {
      int n = nbase + n0 + j;
      float cn = cnorm[n];
#pragma unroll
      for (int i = 0; i < 4; ++i) {
        float r = fmaf(-2.f, acc[i][j], cn);
        if (r < minv[i]) { minv[i] = r; mini[i] = n; }
      }
    }
  }

  // Cross-thread reduce: 16 n-groups per row, lexicographic (val, idx) min.
  const int g = t >> 4;
#pragma unroll
  for (int i = 0; i < 4; ++i) {
    redv[m0 + i][g] = minv[i];
    redi[m0 + i][g] = mini[i];
  }
  __syncthreads();
  if (t < BM) {
    float bv = 3.4e38f;
    int bi = 0x7fffffff;
#pragma unroll
    for (int gg = 0; gg < 16; ++gg) {
      float v = redv[t][gg];
      int ii = redi[t][gg];
      if (v < bv || (v == bv && ii < bi)) { bv = v; bi = ii; }
    }
    idxf[row0 + t] = (float)bi;
  }
}

// ---------------------------------------------------------------------------
// Kernel 3: gather quantized = codes[idx], loss = (1+BETA)*mean(ssd).
// Block 256 = 4 waves, 2 rows/wave (32 lanes x float4 per row).
// ---------------------------------------------------------------------------
__global__ void gather_loss_kernel(const float* __restrict__ x,
                                   const float* __restrict__ codes,
                                   const float* __restrict__ idxf,
                                   float* __restrict__ quant,
                                   float* __restrict__ loss) {
  __shared__ float bsum;
  int t = threadIdx.x;
  if (t == 0) bsum = 0.f;
  __syncthreads();

  int wave = t >> 6;
  int lane = t & 63;
  int half = lane >> 5;
  int l = lane & 31;
  int row = blockIdx.x * 8 + (wave << 1) + half;

  int idx = (int)idxf[row];
  float4 cv = ((const float4*)(codes + (size_t)idx * Dn))[l];
  float4 xv = ((const float4*)(x + (size_t)row * Dn))[l];
  ((float4*)(quant + (size_t)row * Dn))[l] = cv;

  float d0 = xv.x - cv.x, d1 = xv.y - cv.y, d2 = xv.z - cv.z, d3 = xv.w - cv.w;
  float s = d0 * d0 + d1 * d1 + d2 * d2 + d3 * d3;
#pragma unroll
  for (int off = 16; off > 0; off >>= 1) s += __shfl_down(s, off, 32);
  if (l == 0) atomicAdd(&bsum, s);
  __syncthreads();
  if (t == 0) atomicAdd(loss, bsum * (1.25f / 65536.f));
}

// ---------------------------------------------------------------------------
extern "C" void kernel_launch(void* const* d_in, const int* in_sizes, int n_in,
                              void* d_out, int out_size, void* d_ws,
                              size_t ws_size, hipStream_t stream) {
  const float* x = (const float*)d_in[0];
  const float* codes = (const float*)d_in[1];  // [1, C, D] -> [C, D]

  float* quant = (float*)d_out;                      // B*D floats
  float* idxf = quant + (size_t)Bn * Dn;             // B floats (indices)
  float* loss = idxf + Bn;                           // 1 float
  float* cnorm = (float*)d_ws;                       // C floats scratch

  cnorm_kernel<<<Cn / 256, 256, 0, stream>>>(codes, cnorm, loss);
  argmin_kernel<<<Bn / BM, 256, 0, stream>>>(x, codes, cnorm, idxf);
  gather_loss_kernel<<<Bn / 8, 256, 0, stream>>>(x, codes, idxf, quant, loss);
}

// Round 2
// 762.705 us; speedup vs baseline: 1.5660x; 1.5660x over previous
//
#include <hip/hip_runtime.h>

constexpr int Bn = 65536;
constexpr int Cn = 4096;
constexpr int Dn = 128;

typedef short v8s __attribute__((ext_vector_type(8)));
typedef float v16f __attribute__((ext_vector_type(16)));

#define MFMA(a, b, c) __builtin_amdgcn_mfma_f32_32x32x16_bf16((a), (b), (c), 0, 0, 0)

__device__ __forceinline__ unsigned short bf16_rne(float f) {
  unsigned u = __float_as_uint(f);
  return (unsigned short)((u + 0x7fffu + ((u >> 16) & 1u)) >> 16);
}
__device__ __forceinline__ float bf16_to_f32(unsigned short h) {
  return __uint_as_float(((unsigned)h) << 16);
}

// ---------------------------------------------------------------------------
// cnorm (fp64 accum) + zero loss
// ---------------------------------------------------------------------------
__global__ void cnorm_kernel(const float* __restrict__ codes,
                             float* __restrict__ cnorm,
                             float* __restrict__ loss) {
  int n = blockIdx.x * blockDim.x + threadIdx.x;
  if (blockIdx.x == 0 && threadIdx.x == 0) *loss = 0.f;
  if (n >= Cn) return;
  const float4* p = (const float4*)(codes + (size_t)n * Dn);
  double s = 0.0;
#pragma unroll
  for (int i = 0; i < Dn / 4; ++i) {
    float4 v = p[i];
    s += (double)v.x * v.x + (double)v.y * v.y + (double)v.z * v.z +
         (double)v.w * v.w;
  }
  cnorm[n] = (float)s;
}

// ---------------------------------------------------------------------------
// Pack codes into MFMA A-fragment order, hi/lo bf16 planes.
// Fragment (ct, ks): lane l holds code m = 32*ct + (l&31),
// k = 16*ks + 8*(l>>5) + j  (j=0..7). Layout (shorts):
//   frag f = ct*8+ks:  hi at f*1024 + l*8, lo at f*1024 + 512 + l*8.
// ---------------------------------------------------------------------------
__global__ void pack_codes_kernel(const float* __restrict__ codes,
                                  short* __restrict__ pack) {
  int tid = blockIdx.x * 256 + threadIdx.x;  // 65536 threads
  int f = tid >> 6;                          // 0..1023
  int l = tid & 63;
  int ct = f >> 3, ks = f & 7;
  int code = (ct << 5) + (l & 31);
  int kb = (ks << 4) + ((l >> 5) << 3);
  const float* p = codes + (size_t)code * Dn + kb;
  float4 a = ((const float4*)p)[0];
  float4 b = ((const float4*)p)[1];
  float v[8] = {a.x, a.y, a.z, a.w, b.x, b.y, b.z, b.w};
  v8s hi, lo;
#pragma unroll
  for (int j = 0; j < 8; ++j) {
    unsigned short h = bf16_rne(v[j]);
    hi[j] = (short)h;
    lo[j] = (short)bf16_rne(v[j] - bf16_to_f32(h));
  }
  *(v8s*)(pack + (size_t)f * 1024 + l * 8) = hi;
  *(v8s*)(pack + (size_t)f * 1024 + 512 + l * 8) = lo;
}

// ---------------------------------------------------------------------------
// Main kernel: 3-term bf16-split MFMA distance scan + streaming top-2 argmin.
// Block = 64 x-rows, 4 waves each sweep a disjoint 1024-code quarter.
// A = codes (from packed L2 stream), B = x (hi in regs, lo in LDS).
// acc(32x32 C/D): col = lane&31 = x-row, row = (reg&3)+8*(reg>>2)+4*(lane>>5)
//               = code within tile.
// ---------------------------------------------------------------------------
__launch_bounds__(256, 2)
__global__ void argmin_mfma_kernel(const float* __restrict__ x,
                                   const short* __restrict__ pack,
                                   const float* __restrict__ cnorm,
                                   float* __restrict__ idxf,
                                   float* __restrict__ margin) {
  __shared__ __align__(16) short xloLDS[2 * 8 * 64 * 8];  // 16 KB
  __shared__ __align__(16) float cnormLDS[Cn];            // 16 KB
  __shared__ float redv[4][64];
  __shared__ float red2[4][64];
  __shared__ int redi[4][64];

  const int t = threadIdx.x;
  const int w = t >> 6;
  const int l = t & 63;
  const int row0 = blockIdx.x * 64;

  // stage cnorm -> LDS (float4)
  for (int i = t * 4; i < Cn; i += 1024)
    *(float4*)&cnormLDS[i] = *(const float4*)&cnorm[i];

  // Load x B-fragments: hi -> registers (all waves), lo -> LDS (wave 0 writes).
  v8s xhi[2][8];
#pragma unroll
  for (int tt = 0; tt < 2; ++tt) {
#pragma unroll
    for (int ks = 0; ks < 8; ++ks) {
      int xrow = row0 + tt * 32 + (l & 31);
      int kb = ks * 16 + (l >> 5) * 8;
      const float* xp = x + (size_t)xrow * Dn + kb;
      float4 a = ((const float4*)xp)[0];
      float4 b = ((const float4*)xp)[1];
      float v[8] = {a.x, a.y, a.z, a.w, b.x, b.y, b.z, b.w};
      v8s hi, lo;
#pragma unroll
      for (int j = 0; j < 8; ++j) {
        unsigned short h = bf16_rne(v[j]);
        hi[j] = (short)h;
        lo[j] = (short)bf16_rne(v[j] - bf16_to_f32(h));
      }
      xhi[tt][ks] = hi;
      if (w == 0) *(v8s*)&xloLDS[((tt * 8 + ks) * 64 + l) * 8] = lo;
    }
  }
  __syncthreads();

  float min1[2] = {3.4e38f, 3.4e38f};
  float min2[2] = {3.4e38f, 3.4e38f};
  int idx[2] = {0, 0};

  for (int it = 0; it < 16; ++it) {
    const int ct0 = w * 32 + it * 2;  // two 32-code tiles per iteration
    v16f acc[2][2];
#pragma unroll
    for (int m = 0; m < 2; ++m)
#pragma unroll
      for (int tt = 0; tt < 2; ++tt)
#pragma unroll
        for (int i = 0; i < 16; ++i) acc[m][tt][i] = 0.f;

#pragma unroll
    for (int ks = 0; ks < 8; ++ks) {
      const short* pb = pack + ((size_t)ct0 * 8 + ks) * 1024 + l * 8;
      v8s a0h = *(const v8s*)pb;
      v8s a0l = *(const v8s*)(pb + 512);
      v8s a1h = *(const v8s*)(pb + 8192);
      v8s a1l = *(const v8s*)(pb + 8192 + 512);
      v8s b0l = *(const v8s*)&xloLDS[((0 * 8 + ks) * 64 + l) * 8];
      v8s b1l = *(const v8s*)&xloLDS[((1 * 8 + ks) * 64 + l) * 8];
      v8s b0h = xhi[0][ks];
      v8s b1h = xhi[1][ks];
      // hh terms
      acc[0][0] = MFMA(a0h, b0h, acc[0][0]);
      acc[0][1] = MFMA(a0h, b1h, acc[0][1]);
      acc[1][0] = MFMA(a1h, b0h, acc[1][0]);
      acc[1][1] = MFMA(a1h, b1h, acc[1][1]);
      // hl terms (chi * xlo)
      acc[0][0] = MFMA(a0h, b0l, acc[0][0]);
      acc[0][1] = MFMA(a0h, b1l, acc[0][1]);
      acc[1][0] = MFMA(a1h, b0l, acc[1][0]);
      acc[1][1] = MFMA(a1h, b1l, acc[1][1]);
      // lh terms (clo * xhi)
      acc[0][0] = MFMA(a0l, b0h, acc[0][0]);
      acc[0][1] = MFMA(a0l, b1h, acc[0][1]);
      acc[1][0] = MFMA(a1l, b0h, acc[1][0]);
      acc[1][1] = MFMA(a1l, b1h, acc[1][1]);
    }

    // epilogue: key = cnorm - 2*dot, update per-lane top-2
#pragma unroll
    for (int m = 0; m < 2; ++m) {
      const int cb = (ct0 + m) * 32 + (l >> 5) * 4;
#pragma unroll
      for (int r = 0; r < 16; ++r) {
        const int code = cb + (r & 3) + 8 * (r >> 2);
        const float cn = cnormLDS[code];
#pragma unroll
        for (int tt = 0; tt < 2; ++tt) {
          float key = fmaf(-2.f, acc[m][tt][r], cn);
          bool lt = key < min1[tt];
          min2[tt] = lt ? min1[tt] : fminf(min2[tt], key);
          idx[tt] = lt ? code : idx[tt];
          min1[tt] = lt ? key : min1[tt];
        }
      }
    }
  }

  // merge lane pair (l, l^32): same x-row, complementary code rows
#pragma unroll
  for (int tt = 0; tt < 2; ++tt) {
    float o1 = __shfl_xor(min1[tt], 32);
    float o2 = __shfl_xor(min2[tt], 32);
    int oi = __shfl_xor(idx[tt], 32);
    bool sw = (o1 < min1[tt]) || (o1 == min1[tt] && oi < idx[tt]);
    float n1 = sw ? o1 : min1[tt];
    int ni = sw ? oi : idx[tt];
    float big = sw ? min1[tt] : o1;
    float n2 = fminf(fminf(min2[tt], o2), big);
    if (l < 32) {
      redv[w][tt * 32 + l] = n1;
      red2[w][tt * 32 + l] = n2;
      redi[w][tt * 32 + l] = ni;
    }
  }
  __syncthreads();

  if (t < 64) {
    float m1 = 3.4e38f, m2 = 3.4e38f;
    int mi = 0x7fffffff;
#pragma unroll
    for (int ww = 0; ww < 4; ++ww) {
      float a1 = redv[ww][t];
      float a2 = red2[ww][t];
      int ai = redi[ww][t];
      if (a1 < m1 || (a1 == m1 && ai < mi)) {
        m2 = fminf(m1, a2);
        m1 = a1;
        mi = ai;
      } else {
        m2 = fminf(m2, a1);
      }
    }
    idxf[row0 + t] = (float)mi;
    margin[row0 + t] = m2 - m1;
  }
}

// ---------------------------------------------------------------------------
// Exact fp32 rescore for rows with approx margin < TAU.
// ---------------------------------------------------------------------------
__global__ void rescore_kernel(const float* __restrict__ x,
                               const float* __restrict__ codes,
                               const float* __restrict__ cnorm,
                               const float* __restrict__ margin,
                               float* __restrict__ idxf) {
  __shared__ __align__(16) float xrow[Dn];
  __shared__ float rv[256];
  __shared__ int ri[256];
  const float TAU = 0.02f;
  const int t = threadIdx.x;
  const int rows0 = blockIdx.x * 256;

  for (int rr = 0; rr < 256; ++rr) {
    int r = rows0 + rr;
    if (margin[r] >= TAU) continue;  // block-uniform
    if (t < 32) ((float4*)xrow)[t] = ((const float4*)(x + (size_t)r * Dn))[t];
    __syncthreads();
    float bv = 3.4e38f;
    int bi = 0x7fffffff;
    for (int c = t; c < Cn; c += 256) {
      const float4* cp = (const float4*)(codes + (size_t)c * Dn);
      float s = 0.f;
#pragma unroll
      for (int i = 0; i < Dn / 4; ++i) {
        float4 v = cp[i];
        float4 u = ((const float4*)xrow)[i];
        s = fmaf(v.x, u.x, s);
        s = fmaf(v.y, u.y, s);
        s = fmaf(v.z, u.z, s);
        s = fmaf(v.w, u.w, s);
      }
      float key = fmaf(-2.f, s, cnorm[c]);
      if (key < bv) { bv = key; bi = c; }
    }
    rv[t] = bv;
    ri[t] = bi;
    __syncthreads();
    for (int off = 128; off > 0; off >>= 1) {
      if (t < off) {
        float ov = rv[t + off];
        int oi = ri[t + off];
        if (ov < rv[t] || (ov == rv[t] && oi < ri[t])) {
          rv[t] = ov;
          ri[t] = oi;
        }
      }
      __syncthreads();
    }
    if (t == 0) idxf[r] = (float)ri[0];
    __syncthreads();
  }
}

// ---------------------------------------------------------------------------
// Gather + loss (round-1 proven)
// ---------------------------------------------------------------------------
__global__ void gather_loss_kernel(const float* __restrict__ x,
                                   const float* __restrict__ codes,
                                   const float* __restrict__ idxf,
                                   float* __restrict__ quant,
                                   float* __restrict__ loss) {
  __shared__ float bsum;
  int t = threadIdx.x;
  if (t == 0) bsum = 0.f;
  __syncthreads();

  int wave = t >> 6;
  int lane = t & 63;
  int half = lane >> 5;
  int l = lane & 31;
  int row = blockIdx.x * 8 + (wave << 1) + half;

  int idx = (int)idxf[row];
  float4 cv = ((const float4*)(codes + (size_t)idx * Dn))[l];
  float4 xv = ((const float4*)(x + (size_t)row * Dn))[l];
  ((float4*)(quant + (size_t)row * Dn))[l] = cv;

  float d0 = xv.x - cv.x, d1 = xv.y - cv.y, d2 = xv.z - cv.z, d3 = xv.w - cv.w;
  float s = d0 * d0 + d1 * d1 + d2 * d2 + d3 * d3;
#pragma unroll
  for (int off = 16; off > 0; off >>= 1) s += __shfl_down(s, off, 32);
  if (l == 0) atomicAdd(&bsum, s);
  __syncthreads();
  if (t == 0) atomicAdd(loss, bsum * (1.25f / 65536.f));
}

// ---------------------------------------------------------------------------
extern "C" void kernel_launch(void* const* d_in, const int* in_sizes, int n_in,
                              void* d_out, int out_size, void* d_ws,
                              size_t ws_size, hipStream_t stream) {
  const float* x = (const float*)d_in[0];
  const float* codes = (const float*)d_in[1];

  float* quant = (float*)d_out;            // B*D floats (also scratch early)
  float* idxf = quant + (size_t)Bn * Dn;   // B floats
  float* loss = idxf + Bn;                 // 1 float
  float* cnorm = (float*)d_ws;             // C floats (ws proven >= 16 KB)

  // Scratch inside the quant region (fully overwritten by gather at the end):
  short* pack = (short*)quant;                    // 2 MB packed codes
  float* margin = quant + (1 << 20);              // 256 KB margins

  cnorm_kernel<<<Cn / 256, 256, 0, stream>>>(codes, cnorm, loss);
  pack_codes_kernel<<<256, 256, 0, stream>>>(codes, pack);
  argmin_mfma_kernel<<<Bn / 64, 256, 0, stream>>>(x, pack, cnorm, idxf, margin);
  rescore_kernel<<<Bn / 256, 256, 0, stream>>>(x, codes, cnorm, margin, idxf);
  gather_loss_kernel<<<Bn / 8, 256, 0, stream>>>(x, codes, idxf, quant, loss);
}

// Round 3
// 635.421 us; speedup vs baseline: 1.8797x; 1.2003x over previous
//
#include <hip/hip_runtime.h>

constexpr int Bn = 65536;
constexpr int Cn = 4096;
constexpr int Dn = 128;
constexpr float TAU = 2e-3f;

typedef short v8s __attribute__((ext_vector_type(8)));
typedef float v16f __attribute__((ext_vector_type(16)));

#define MFMA(a, b, c) __builtin_amdgcn_mfma_f32_32x32x16_bf16((a), (b), (c), 0, 0, 0)

__device__ __forceinline__ unsigned short bf16_rne(float f) {
  unsigned u = __float_as_uint(f);
  return (unsigned short)((u + 0x7fffu + ((u >> 16) & 1u)) >> 16);
}
__device__ __forceinline__ float bf16_to_f32(unsigned short h) {
  return __uint_as_float(((unsigned)h) << 16);
}

// ---------------------------------------------------------------------------
// cnorm (fp64 accum) + zero loss + zero flag counter
// ---------------------------------------------------------------------------
__global__ void cnorm_kernel(const float* __restrict__ codes,
                             float* __restrict__ cnorm,
                             float* __restrict__ loss,
                             int* __restrict__ flagcount) {
  int n = blockIdx.x * blockDim.x + threadIdx.x;
  if (blockIdx.x == 0 && threadIdx.x == 0) {
    *loss = 0.f;
    *flagcount = 0;
  }
  if (n >= Cn) return;
  const float4* p = (const float4*)(codes + (size_t)n * Dn);
  double s = 0.0;
#pragma unroll
  for (int i = 0; i < Dn / 4; ++i) {
    float4 v = p[i];
    s += (double)v.x * v.x + (double)v.y * v.y + (double)v.z * v.z +
         (double)v.w * v.w;
  }
  cnorm[n] = (float)s;
}

// ---------------------------------------------------------------------------
// Pack codes into MFMA A-fragment order, hi/lo bf16 planes (round-2 proven).
// Fragment (ct, ks): lane l holds code m = 32*ct + (l&31),
// k = 16*ks + 8*(l>>5) + j. hi at f*1024 + l*8, lo at +512 (f = ct*8+ks).
// ---------------------------------------------------------------------------
__global__ void pack_codes_kernel(const float* __restrict__ codes,
                                  short* __restrict__ pack) {
  int tid = blockIdx.x * 256 + threadIdx.x;
  int f = tid >> 6;
  int l = tid & 63;
  int ct = f >> 3, ks = f & 7;
  int code = (ct << 5) + (l & 31);
  int kb = (ks << 4) + ((l >> 5) << 3);
  const float* p = codes + (size_t)code * Dn + kb;
  float4 a = ((const float4*)p)[0];
  float4 b = ((const float4*)p)[1];
  float v[8] = {a.x, a.y, a.z, a.w, b.x, b.y, b.z, b.w};
  v8s hi, lo;
#pragma unroll
  for (int j = 0; j < 8; ++j) {
    unsigned short h = bf16_rne(v[j]);
    hi[j] = (short)h;
    lo[j] = (short)bf16_rne(v[j] - bf16_to_f32(h));
  }
  *(v8s*)(pack + (size_t)f * 1024 + l * 8) = hi;
  *(v8s*)(pack + (size_t)f * 1024 + 512 + l * 8) = lo;
}

// ---------------------------------------------------------------------------
// Main: 3-term bf16-split MFMA scan, BM=128 rows/block, 4 waves sweep
// disjoint 1024-code quarters. A = packed codes (L2 stream), B = x
// (hi in regs: 4 tiles x 8 ks, lo in LDS). Per ks: 2 pack loads -> 12 MFMA.
// C/D 32x32: col = lane&31 = x-row, code-row = (r&3)+8*(r>>2)+4*(lane>>5).
// ---------------------------------------------------------------------------
__launch_bounds__(256, 2)
__global__ void argmin_mfma_kernel(const float* __restrict__ x,
                                   const short* __restrict__ pack,
                                   const float* __restrict__ cnorm,
                                   float* __restrict__ idxf,
                                   int* __restrict__ flaglist,
                                   int* __restrict__ flagcount) {
  __shared__ __align__(16) short xloLDS[4 * 8 * 64 * 8];  // 32 KB
  __shared__ __align__(16) float cnormLDS[Cn];            // 16 KB
  __shared__ float redv[4][128];
  __shared__ float red2[4][128];
  __shared__ int redi[4][128];

  const int t = threadIdx.x;
  const int w = t >> 6;
  const int l = t & 63;
  const int row0 = blockIdx.x * 128;

  for (int i = t * 4; i < Cn; i += 1024)
    *(float4*)&cnormLDS[i] = *(const float4*)&cnorm[i];

  // x B-fragments: hi -> regs (every wave, all 4 tiles), lo -> LDS (wave 0).
  v8s xhi[4][8];
#pragma unroll
  for (int tt = 0; tt < 4; ++tt) {
#pragma unroll
    for (int ks = 0; ks < 8; ++ks) {
      int xrow = row0 + tt * 32 + (l & 31);
      int kb = ks * 16 + (l >> 5) * 8;
      const float* xp = x + (size_t)xrow * Dn + kb;
      float4 a = ((const float4*)xp)[0];
      float4 b = ((const float4*)xp)[1];
      float v[8] = {a.x, a.y, a.z, a.w, b.x, b.y, b.z, b.w};
      v8s hi, lo;
#pragma unroll
      for (int j = 0; j < 8; ++j) {
        unsigned short h = bf16_rne(v[j]);
        hi[j] = (short)h;
        lo[j] = (short)bf16_rne(v[j] - bf16_to_f32(h));
      }
      xhi[tt][ks] = hi;
      if (w == 0) *(v8s*)&xloLDS[((tt * 8 + ks) * 64 + l) * 8] = lo;
    }
  }
  __syncthreads();

  float min1[4] = {3.4e38f, 3.4e38f, 3.4e38f, 3.4e38f};
  float min2[4] = {3.4e38f, 3.4e38f, 3.4e38f, 3.4e38f};
  int idx[4] = {0, 0, 0, 0};

  for (int it = 0; it < 32; ++it) {
    const int ct = w * 32 + it;
    v16f acc[4];
#pragma unroll
    for (int tt = 0; tt < 4; ++tt)
#pragma unroll
      for (int i = 0; i < 16; ++i) acc[tt][i] = 0.f;

#pragma unroll
    for (int ks = 0; ks < 8; ++ks) {
      const short* pb = pack + ((size_t)ct * 8 + ks) * 1024 + l * 8;
      v8s a_h = *(const v8s*)pb;
      v8s a_l = *(const v8s*)(pb + 512);
      v8s b_l0 = *(const v8s*)&xloLDS[((0 * 8 + ks) * 64 + l) * 8];
      v8s b_l1 = *(const v8s*)&xloLDS[((1 * 8 + ks) * 64 + l) * 8];
      v8s b_l2 = *(const v8s*)&xloLDS[((2 * 8 + ks) * 64 + l) * 8];
      v8s b_l3 = *(const v8s*)&xloLDS[((3 * 8 + ks) * 64 + l) * 8];
      acc[0] = MFMA(a_h, xhi[0][ks], acc[0]);
      acc[1] = MFMA(a_h, xhi[1][ks], acc[1]);
      acc[2] = MFMA(a_h, xhi[2][ks], acc[2]);
      acc[3] = MFMA(a_h, xhi[3][ks], acc[3]);
      acc[0] = MFMA(a_h, b_l0, acc[0]);
      acc[1] = MFMA(a_h, b_l1, acc[1]);
      acc[2] = MFMA(a_h, b_l2, acc[2]);
      acc[3] = MFMA(a_h, b_l3, acc[3]);
      acc[0] = MFMA(a_l, xhi[0][ks], acc[0]);
      acc[1] = MFMA(a_l, xhi[1][ks], acc[1]);
      acc[2] = MFMA(a_l, xhi[2][ks], acc[2]);
      acc[3] = MFMA(a_l, xhi[3][ks], acc[3]);
    }

    // Epilogue: cn broadcast-loaded once per tile (4 x float4), then 64 keys.
    const int base = ct * 32 + 4 * (l >> 5);
    float4 cn4[4];
#pragma unroll
    for (int g = 0; g < 4; ++g) cn4[g] = *(const float4*)&cnormLDS[base + 8 * g];
#pragma unroll
    for (int r = 0; r < 16; ++r) {
      const int g = r >> 2, wi = r & 3;
      const int code = base + 8 * g + wi;
      const float cn = ((const float*)&cn4[g])[wi];
#pragma unroll
      for (int tt = 0; tt < 4; ++tt) {
        float key = fmaf(-2.f, acc[tt][r], cn);
        bool lt = key < min1[tt];
        min2[tt] = lt ? min1[tt] : fminf(min2[tt], key);
        idx[tt] = lt ? code : idx[tt];
        min1[tt] = lt ? key : min1[tt];
      }
    }
  }

  // Merge lane pair (l, l^32): same x-row, complementary code rows.
#pragma unroll
  for (int tt = 0; tt < 4; ++tt) {
    float o1 = __shfl_xor(min1[tt], 32);
    float o2 = __shfl_xor(min2[tt], 32);
    int oi = __shfl_xor(idx[tt], 32);
    bool sw = (o1 < min1[tt]) || (o1 == min1[tt] && oi < idx[tt]);
    float n1 = sw ? o1 : min1[tt];
    int ni = sw ? oi : idx[tt];
    float big = sw ? min1[tt] : o1;
    float n2 = fminf(fminf(min2[tt], o2), big);
    if (l < 32) {
      redv[w][tt * 32 + l] = n1;
      red2[w][tt * 32 + l] = n2;
      redi[w][tt * 32 + l] = ni;
    }
  }
  __syncthreads();

  if (t < 128) {
    float m1 = 3.4e38f, m2 = 3.4e38f;
    int mi = 0x7fffffff;
#pragma unroll
    for (int ww = 0; ww < 4; ++ww) {
      float a1 = redv[ww][t];
      float a2 = red2[ww][t];
      int ai = redi[ww][t];
      if (a1 < m1 || (a1 == m1 && ai < mi)) {
        m2 = fminf(m1, a2);
        m1 = a1;
        mi = ai;
      } else {
        m2 = fminf(m2, a1);
      }
    }
    const int row = row0 + t;
    idxf[row] = (float)mi;
    if (m2 - m1 < TAU) {
      int pos = atomicAdd(flagcount, 1);
      flaglist[pos] = row;
    }
  }
}

// ---------------------------------------------------------------------------
// Exact fp32 rescore: grid-stride block-per-flagged-row over compacted list.
// All threads share one LDS x-row (broadcast reads). Round-2-proven scan.
// ---------------------------------------------------------------------------
__global__ void rescore_kernel(const float* __restrict__ x,
                               const float* __restrict__ codes,
                               const float* __restrict__ cnorm,
                               const int* __restrict__ flaglist,
                               const int* __restrict__ flagcount,
                               float* __restrict__ idxf) {
  __shared__ __align__(16) float xrow[Dn];
  __shared__ float rv[256];
  __shared__ int ri[256];
  const int t = threadIdx.x;
  const int cnt = *flagcount;

  for (int j = blockIdx.x; j < cnt; j += gridDim.x) {
    const int r = flaglist[j];
    __syncthreads();  // protect xrow/rv/ri from previous iteration
    if (t < 32) ((float4*)xrow)[t] = ((const float4*)(x + (size_t)r * Dn))[t];
    __syncthreads();
    float bv = 3.4e38f;
    int bi = 0x7fffffff;
    for (int c = t; c < Cn; c += 256) {
      const float4* cp = (const float4*)(codes + (size_t)c * Dn);
      float s = 0.f;
#pragma unroll
      for (int i = 0; i < Dn / 4; ++i) {
        float4 v = cp[i];
        float4 u = ((const float4*)xrow)[i];
        s = fmaf(v.x, u.x, s);
        s = fmaf(v.y, u.y, s);
        s = fmaf(v.z, u.z, s);
        s = fmaf(v.w, u.w, s);
      }
      float key = fmaf(-2.f, s, cnorm[c]);
      if (key < bv) { bv = key; bi = c; }
    }
    rv[t] = bv;
    ri[t] = bi;
    __syncthreads();
    for (int off = 128; off > 0; off >>= 1) {
      if (t < off) {
        float ov = rv[t + off];
        int oi = ri[t + off];
        if (ov < rv[t] || (ov == rv[t] && oi < ri[t])) {
          rv[t] = ov;
          ri[t] = oi;
        }
      }
      __syncthreads();
    }
    if (t == 0) idxf[r] = (float)ri[0];
  }
}

// ---------------------------------------------------------------------------
// Gather + loss (round-1 proven)
// ---------------------------------------------------------------------------
__global__ void gather_loss_kernel(const float* __restrict__ x,
                                   const float* __restrict__ codes,
                                   const float* __restrict__ idxf,
                                   float* __restrict__ quant,
                                   float* __restrict__ loss) {
  __shared__ float bsum;
  int t = threadIdx.x;
  if (t == 0) bsum = 0.f;
  __syncthreads();

  int wave = t >> 6;
  int lane = t & 63;
  int half = lane >> 5;
  int l = lane & 31;
  int row = blockIdx.x * 8 + (wave << 1) + half;

  int idx = (int)idxf[row];
  float4 cv = ((const float4*)(codes + (size_t)idx * Dn))[l];
  float4 xv = ((const float4*)(x + (size_t)row * Dn))[l];
  ((float4*)(quant + (size_t)row * Dn))[l] = cv;

  float d0 = xv.x - cv.x, d1 = xv.y - cv.y, d2 = xv.z - cv.z, d3 = xv.w - cv.w;
  float s = d0 * d0 + d1 * d1 + d2 * d2 + d3 * d3;
#pragma unroll
  for (int off = 16; off > 0; off >>= 1) s += __shfl_down(s, off, 32);
  if (l == 0) atomicAdd(&bsum, s);
  __syncthreads();
  if (t == 0) atomicAdd(loss, bsum * (1.25f / 65536.f));
}

// ---------------------------------------------------------------------------
extern "C" void kernel_launch(void* const* d_in, const int* in_sizes, int n_in,
                              void* d_out, int out_size, void* d_ws,
                              size_t ws_size, hipStream_t stream) {
  const float* x = (const float*)d_in[0];
  const float* codes = (const float*)d_in[1];

  float* quant = (float*)d_out;            // B*D floats (scratch until gather)
  float* idxf = quant + (size_t)Bn * Dn;   // B floats
  float* loss = idxf + Bn;                 // 1 float
  float* cnorm = (float*)d_ws;             // 16 KB (proven available)

  // Scratch in the quant region (pack: first 2 MB; flag data at +4 MB):
  short* pack = (short*)quant;
  int* flagcount = (int*)(quant + (1 << 20));
  int* flaglist = flagcount + 1;

  cnorm_kernel<<<Cn / 256, 256, 0, stream>>>(codes, cnorm, loss, flagcount);
  pack_codes_kernel<<<256, 256, 0, stream>>>(codes, pack);
  argmin_mfma_kernel<<<Bn / 128, 256, 0, stream>>>(x, pack, cnorm, idxf,
                                                   flaglist, flagcount);
  rescore_kernel<<<1024, 256, 0, stream>>>(x, codes, cnorm, flaglist,
                                           flagcount, idxf);
  gather_loss_kernel<<<Bn / 8, 256, 0, stream>>>(x, codes, idxf, quant, loss);
}

// Round 4
// 463.376 us; speedup vs baseline: 2.5777x; 1.3713x over previous
//
#include <hip/hip_runtime.h>

constexpr int Bn = 65536;
constexpr int Cn = 4096;
constexpr int Dn = 128;
constexpr float TAU = 5e-4f;

typedef short v8s __attribute__((ext_vector_type(8)));
typedef float v16f __attribute__((ext_vector_type(16)));

#define MFMA(a, b, c) __builtin_amdgcn_mfma_f32_32x32x16_bf16((a), (b), (c), 0, 0, 0)

__device__ __forceinline__ unsigned short bf16_rne(float f) {
  unsigned u = __float_as_uint(f);
  return (unsigned short)((u + 0x7fffu + ((u >> 16) & 1u)) >> 16);
}
__device__ __forceinline__ float bf16_to_f32(unsigned short h) {
  return __uint_as_float(((unsigned)h) << 16);
}

// ---------------------------------------------------------------------------
// cnorm (fp64 accum) + zero loss + zero flag counter
// ---------------------------------------------------------------------------
__global__ void cnorm_kernel(const float* __restrict__ codes,
                             float* __restrict__ cnorm,
                             float* __restrict__ loss,
                             int* __restrict__ flagcount) {
  int n = blockIdx.x * blockDim.x + threadIdx.x;
  if (blockIdx.x == 0 && threadIdx.x == 0) {
    *loss = 0.f;
    *flagcount = 0;
  }
  if (n >= Cn) return;
  const float4* p = (const float4*)(codes + (size_t)n * Dn);
  double s = 0.0;
#pragma unroll
  for (int i = 0; i < Dn / 4; ++i) {
    float4 v = p[i];
    s += (double)v.x * v.x + (double)v.y * v.y + (double)v.z * v.z +
         (double)v.w * v.w;
  }
  cnorm[n] = (float)s;
}

// ---------------------------------------------------------------------------
// Pack codes into MFMA A-fragment order, hi/lo bf16 planes (R2/R3 proven).
// Fragment (ct, ks): lane l holds code m = 32*ct + (l&31),
// k = 16*ks + 8*(l>>5) + j. hi at f*1024 + l*8 shorts, lo at +512 (f=ct*8+ks).
// One ct tile = 16 KB contiguous.
// ---------------------------------------------------------------------------
__global__ void pack_codes_kernel(const float* __restrict__ codes,
                                  short* __restrict__ pack) {
  int tid = blockIdx.x * 256 + threadIdx.x;
  int f = tid >> 6;
  int l = tid & 63;
  int ct = f >> 3, ks = f & 7;
  int code = (ct << 5) + (l & 31);
  int kb = (ks << 4) + ((l >> 5) << 3);
  const float* p = codes + (size_t)code * Dn + kb;
  float4 a = ((const float4*)p)[0];
  float4 b = ((const float4*)p)[1];
  float v[8] = {a.x, a.y, a.z, a.w, b.x, b.y, b.z, b.w};
  v8s hi, lo;
#pragma unroll
  for (int j = 0; j < 8; ++j) {
    unsigned short h = bf16_rne(v[j]);
    hi[j] = (short)h;
    lo[j] = (short)bf16_rne(v[j] - bf16_to_f32(h));
  }
  *(v8s*)(pack + (size_t)f * 1024 + l * 8) = hi;
  *(v8s*)(pack + (size_t)f * 1024 + 512 + l * 8) = lo;
}

// ---------------------------------------------------------------------------
// Main: block-cooperative LDS-staged sweep. Block = 256 rows x 2048 codes
// (code-half h = blockIdx&1). 4 waves co-sweep the same ct tile from a
// double-buffered LDS stage (global_load_lds w=16); wave owns 64 rows
// (2 tiles, x hi/lo fragments in registers). Per ks: 2 ds_read_b128 -> 6 MFMA.
// C/D 32x32: col = lane&31 = x-row, code-row = (r&3)+8*(r>>2)+4*(lane>>5).
// ---------------------------------------------------------------------------
__launch_bounds__(256, 2)
__global__ void argmin_mfma_kernel(const float* __restrict__ x,
                                   const short* __restrict__ pack,
                                   const float* __restrict__ cnorm,
                                   float* __restrict__ pm1,
                                   float* __restrict__ pm2,
                                   float* __restrict__ pidx) {
  __shared__ __align__(16) short packLDS[2][8192];  // 2 x 16 KB
  __shared__ __align__(16) float cnLDS[2048];       // 8 KB (this half's cnorm)

  const int t = threadIdx.x;
  const int w = t >> 6;
  const int l = t & 63;
  const int h = blockIdx.x & 1;
  const int row0 = (blockIdx.x >> 1) * 256;

  // cnorm half -> LDS
  for (int i = t * 4; i < 2048; i += 1024)
    *(float4*)&cnLDS[i] = *(const float4*)&cnorm[h * 2048 + i];

  // x fragments hi/lo -> registers. Wave w owns rows row0+w*64+tt*32+(l&31).
  v8s xhi[2][8], xlo[2][8];
#pragma unroll
  for (int tt = 0; tt < 2; ++tt) {
#pragma unroll
    for (int ks = 0; ks < 8; ++ks) {
      int xrow = row0 + w * 64 + tt * 32 + (l & 31);
      int kb = ks * 16 + (l >> 5) * 8;
      const float* xp = x + (size_t)xrow * Dn + kb;
      float4 a = ((const float4*)xp)[0];
      float4 b = ((const float4*)xp)[1];
      float v[8] = {a.x, a.y, a.z, a.w, b.x, b.y, b.z, b.w};
      v8s hi, lo;
#pragma unroll
      for (int j = 0; j < 8; ++j) {
        unsigned short hh = bf16_rne(v[j]);
        hi[j] = (short)hh;
        lo[j] = (short)bf16_rne(v[j] - bf16_to_f32(hh));
      }
      xhi[tt][ks] = hi;
      xlo[tt][ks] = lo;
    }
  }

  // Async stage of one 16 KB ct tile: wave w DMAs bytes [w*1024 + i*4096).
  const char* packbase =
      (const char*)pack + (size_t)(h * 64) * 16384 + w * 1024 + l * 16;
  auto stage = [&](int ct, int bufi) {
    const char* src = packbase + (size_t)ct * 16384;
    char* dst = (char*)&packLDS[bufi][0] + w * 1024;  // wave-uniform base
#pragma unroll
    for (int i = 0; i < 4; ++i) {
      __builtin_amdgcn_global_load_lds(
          (const __attribute__((address_space(1))) unsigned*)(src + i * 4096),
          (__attribute__((address_space(3))) unsigned*)(dst + i * 4096), 16, 0,
          0);
    }
  };

  stage(0, 0);
  __syncthreads();

  float min1[2] = {3.4e38f, 3.4e38f};
  float min2[2] = {3.4e38f, 3.4e38f};
  int idx[2] = {0, 0};

  for (int it = 0; it < 64; ++it) {
    const int cur = it & 1;
    if (it + 1 < 64) stage(it + 1, cur ^ 1);

    v16f acc0, acc1;
#pragma unroll
    for (int i = 0; i < 16; ++i) {
      acc0[i] = 0.f;
      acc1[i] = 0.f;
    }

#pragma unroll
    for (int ks = 0; ks < 8; ++ks) {
      const short* pb = &packLDS[cur][ks * 1024 + l * 8];
      v8s a_h = *(const v8s*)pb;
      v8s a_l = *(const v8s*)(pb + 512);
      acc0 = MFMA(a_h, xhi[0][ks], acc0);
      acc1 = MFMA(a_h, xhi[1][ks], acc1);
      acc0 = MFMA(a_h, xlo[0][ks], acc0);
      acc1 = MFMA(a_h, xlo[1][ks], acc1);
      acc0 = MFMA(a_l, xhi[0][ks], acc0);
      acc1 = MFMA(a_l, xhi[1][ks], acc1);
    }

    // Epilogue: key = cnorm - 2*dot; per-lane top-2 (ascending code order
    // within lane + strict '<' = first-index tie-break).
    const int lbase = it * 32 + 4 * (l >> 5);  // local code idx in half
    float4 cn4[4];
#pragma unroll
    for (int g = 0; g < 4; ++g)
      cn4[g] = *(const float4*)&cnLDS[lbase + 8 * g];
#pragma unroll
    for (int r = 0; r < 16; ++r) {
      const int g = r >> 2, wi = r & 3;
      const int code = h * 2048 + lbase + 8 * g + wi;  // global code idx
      const float cn = ((const float*)&cn4[g])[wi];
      float k0 = fmaf(-2.f, acc0[r], cn);
      bool lt0 = k0 < min1[0];
      min2[0] = lt0 ? min1[0] : fminf(min2[0], k0);
      idx[0] = lt0 ? code : idx[0];
      min1[0] = lt0 ? k0 : min1[0];
      float k1 = fmaf(-2.f, acc1[r], cn);
      bool lt1 = k1 < min1[1];
      min2[1] = lt1 ? min1[1] : fminf(min2[1], k1);
      idx[1] = lt1 ? code : idx[1];
      min1[1] = lt1 ? k1 : min1[1];
    }
    __syncthreads();  // all waves done with buf[cur]; DMA for cur^1 drained
  }

  // Merge lane pair (l, l^32): same x-row, complementary code rows.
#pragma unroll
  for (int tt = 0; tt < 2; ++tt) {
    float o1 = __shfl_xor(min1[tt], 32);
    float o2 = __shfl_xor(min2[tt], 32);
    int oi = __shfl_xor(idx[tt], 32);
    bool sw = (o1 < min1[tt]) || (o1 == min1[tt] && oi < idx[tt]);
    float n1 = sw ? o1 : min1[tt];
    int ni = sw ? oi : idx[tt];
    float big = sw ? min1[tt] : o1;
    float n2 = fminf(fminf(min2[tt], o2), big);
    if (l < 32) {
      int row = row0 + w * 64 + tt * 32 + l;
      pm1[h * Bn + row] = n1;
      pm2[h * Bn + row] = n2;
      pidx[h * Bn + row] = (float)ni;
    }
  }
}

// ---------------------------------------------------------------------------
// Merge the two code-half partials; write idxf; flag small-margin rows.
// Halves are disjoint code ranges; half0 wins exact ties (lower index).
// ---------------------------------------------------------------------------
__global__ void merge_kernel(const float* __restrict__ pm1,
                             const float* __restrict__ pm2,
                             const float* __restrict__ pidx,
                             float* __restrict__ idxf,
                             int* __restrict__ flaglist,
                             int* __restrict__ flagcount) {
  int r = blockIdx.x * 256 + threadIdx.x;
  float a1 = pm1[r], b1 = pm1[Bn + r];
  float a2 = pm2[r], b2 = pm2[Bn + r];
  float ai = pidx[r], bi = pidx[Bn + r];
  bool a = (a1 <= b1);
  float m1 = a ? a1 : b1;
  float mi = a ? ai : bi;
  float m2 = a ? fminf(a2, b1) : fminf(b2, a1);
  idxf[r] = mi;
  if (m2 - m1 < TAU) {
    int p = atomicAdd(flagcount, 1);
    flaglist[p] = r;
  }
}

// ---------------------------------------------------------------------------
// Exact fp32 rescore of flagged rows (grid-stride block-per-row).
// ---------------------------------------------------------------------------
__global__ void rescore_kernel(const float* __restrict__ x,
                               const float* __restrict__ codes,
                               const float* __restrict__ cnorm,
                               const int* __restrict__ flaglist,
                               const int* __restrict__ flagcount,
                               float* __restrict__ idxf) {
  __shared__ __align__(16) float xrow[Dn];
  __shared__ float rv[256];
  __shared__ int ri[256];
  const int t = threadIdx.x;
  const int cnt = *flagcount;

  for (int j = blockIdx.x; j < cnt; j += gridDim.x) {
    const int r = flaglist[j];
    __syncthreads();
    if (t < 32) ((float4*)xrow)[t] = ((const float4*)(x + (size_t)r * Dn))[t];
    __syncthreads();
    float bv = 3.4e38f;
    int bi = 0x7fffffff;
    for (int c = t; c < Cn; c += 256) {
      const float4* cp = (const float4*)(codes + (size_t)c * Dn);
      float s = 0.f;
#pragma unroll
      for (int i = 0; i < Dn / 4; ++i) {
        float4 v = cp[i];
        float4 u = ((const float4*)xrow)[i];
        s = fmaf(v.x, u.x, s);
        s = fmaf(v.y, u.y, s);
        s = fmaf(v.z, u.z, s);
        s = fmaf(v.w, u.w, s);
      }
      float key = fmaf(-2.f, s, cnorm[c]);
      if (key < bv) { bv = key; bi = c; }
    }
    rv[t] = bv;
    ri[t] = bi;
    __syncthreads();
    for (int off = 128; off > 0; off >>= 1) {
      if (t < off) {
        float ov = rv[t + off];
        int oi = ri[t + off];
        if (ov < rv[t] || (ov == rv[t] && oi < ri[t])) {
          rv[t] = ov;
          ri[t] = oi;
        }
      }
      __syncthreads();
    }
    if (t == 0) idxf[r] = (float)ri[0];
  }
}

// ---------------------------------------------------------------------------
// Gather + loss (proven)
// ---------------------------------------------------------------------------
__global__ void gather_loss_kernel(const float* __restrict__ x,
                                   const float* __restrict__ codes,
                                   const float* __restrict__ idxf,
                                   float* __restrict__ quant,
                                   float* __restrict__ loss) {
  __shared__ float bsum;
  int t = threadIdx.x;
  if (t == 0) bsum = 0.f;
  __syncthreads();

  int wave = t >> 6;
  int lane = t & 63;
  int half = lane >> 5;
  int l = lane & 31;
  int row = blockIdx.x * 8 + (wave << 1) + half;

  int idx = (int)idxf[row];
  float4 cv = ((const float4*)(codes + (size_t)idx * Dn))[l];
  float4 xv = ((const float4*)(x + (size_t)row * Dn))[l];
  ((float4*)(quant + (size_t)row * Dn))[l] = cv;

  float d0 = xv.x - cv.x, d1 = xv.y - cv.y, d2 = xv.z - cv.z, d3 = xv.w - cv.w;
  float s = d0 * d0 + d1 * d1 + d2 * d2 + d3 * d3;
#pragma unroll
  for (int off = 16; off > 0; off >>= 1) s += __shfl_down(s, off, 32);
  if (l == 0) atomicAdd(&bsum, s);
  __syncthreads();
  if (t == 0) atomicAdd(loss, bsum * (1.25f / 65536.f));
}

// ---------------------------------------------------------------------------
extern "C" void kernel_launch(void* const* d_in, const int* in_sizes, int n_in,
                              void* d_out, int out_size, void* d_ws,
                              size_t ws_size, hipStream_t stream) {
  const float* x = (const float*)d_in[0];
  const float* codes = (const float*)d_in[1];

  float* quant = (float*)d_out;            // B*D floats (scratch until gather)
  float* idxf = quant + (size_t)Bn * Dn;   // B floats
  float* loss = idxf + Bn;                 // 1 float
  float* cnorm = (float*)d_ws;             // 16 KB

  // Scratch inside the quant region (dead before gather writes quant):
  short* pack = (short*)quant;             // 2 MB @ 0
  int* flagcount = (int*)(quant + (1 << 20));  // @ 4 MB
  int* flaglist = flagcount + 1;               // up to 256 KB
  float* pm1 = quant + (2 << 20);              // @ 8 MB, 2*Bn floats
  float* pm2 = pm1 + 2 * Bn;
  float* pidx = pm2 + 2 * Bn;

  cnorm_kernel<<<Cn / 256, 256, 0, stream>>>(codes, cnorm, loss, flagcount);
  pack_codes_kernel<<<256, 256, 0, stream>>>(codes, pack);
  argmin_mfma_kernel<<<512, 256, 0, stream>>>(x, pack, cnorm, pm1, pm2, pidx);
  merge_kernel<<<Bn / 256, 256, 0, stream>>>(pm1, pm2, pidx, idxf, flaglist,
                                             flagcount);
  rescore_kernel<<<2048, 256, 0, stream>>>(x, codes, cnorm, flaglist,
                                           flagcount, idxf);
  gather_loss_kernel<<<Bn / 8, 256, 0, stream>>>(x, codes, idxf, quant, loss);
}

// Round 5
// 383.275 us; speedup vs baseline: 3.1164x; 1.2090x over previous
//
#include <hip/hip_runtime.h>

constexpr int Bn = 65536;
constexpr int Cn = 4096;
constexpr int Dn = 128;
constexpr float TAU = 5e-4f;

typedef short v8s __attribute__((ext_vector_type(8)));
typedef float v16f __attribute__((ext_vector_type(16)));

#define MFMA(a, b, c) __builtin_amdgcn_mfma_f32_32x32x16_bf16((a), (b), (c), 0, 0, 0)

__device__ __forceinline__ unsigned short bf16_rne(float f) {
  unsigned u = __float_as_uint(f);
  return (unsigned short)((u + 0x7fffu + ((u >> 16) & 1u)) >> 16);
}
__device__ __forceinline__ float bf16_to_f32(unsigned short h) {
  return __uint_as_float(((unsigned)h) << 16);
}

// ---------------------------------------------------------------------------
// cnorm (fp64 accum) + zero loss + zero flag counter
// ---------------------------------------------------------------------------
__global__ void cnorm_kernel(const float* __restrict__ codes,
                             float* __restrict__ cnorm,
                             float* __restrict__ loss,
                             int* __restrict__ flagcount) {
  int n = blockIdx.x * blockDim.x + threadIdx.x;
  if (blockIdx.x == 0 && threadIdx.x == 0) {
    *loss = 0.f;
    *flagcount = 0;
  }
  if (n >= Cn) return;
  const float4* p = (const float4*)(codes + (size_t)n * Dn);
  double s = 0.0;
#pragma unroll
  for (int i = 0; i < Dn / 4; ++i) {
    float4 v = p[i];
    s += (double)v.x * v.x + (double)v.y * v.y + (double)v.z * v.z +
         (double)v.w * v.w;
  }
  cnorm[n] = (float)s;
}

// ---------------------------------------------------------------------------
// Pack codes into MFMA A-fragment order, hi/lo bf16 planes (proven R2-R4).
// ---------------------------------------------------------------------------
__global__ void pack_codes_kernel(const float* __restrict__ codes,
                                  short* __restrict__ pack) {
  int tid = blockIdx.x * 256 + threadIdx.x;
  int f = tid >> 6;
  int l = tid & 63;
  int ct = f >> 3, ks = f & 7;
  int code = (ct << 5) + (l & 31);
  int kb = (ks << 4) + ((l >> 5) << 3);
  const float* p = codes + (size_t)code * Dn + kb;
  float4 a = ((const float4*)p)[0];
  float4 b = ((const float4*)p)[1];
  float v[8] = {a.x, a.y, a.z, a.w, b.x, b.y, b.z, b.w};
  v8s hi, lo;
#pragma unroll
  for (int j = 0; j < 8; ++j) {
    unsigned short h = bf16_rne(v[j]);
    hi[j] = (short)h;
    lo[j] = (short)bf16_rne(v[j] - bf16_to_f32(h));
  }
  *(v8s*)(pack + (size_t)f * 1024 + l * 8) = hi;
  *(v8s*)(pack + (size_t)f * 1024 + 512 + l * 8) = lo;
}

// ---------------------------------------------------------------------------
// Main: R4 structure + software-pipelined epilogue (acc double-buffer).
// Each barrier-to-barrier segment contains MFMA(it) AND epilogue(it-1) so
// the in-order wave interleaves VALU into the MFMA pipe shadow (de-phase-lock).
// ---------------------------------------------------------------------------
__launch_bounds__(256, 2)
__global__ void argmin_mfma_kernel(const float* __restrict__ x,
                                   const short* __restrict__ pack,
                                   const float* __restrict__ cnorm,
                                   float* __restrict__ pm1,
                                   float* __restrict__ pm2,
                                   float* __restrict__ pidx) {
  __shared__ __align__(16) short packLDS[2][8192];  // 2 x 16 KB
  __shared__ __align__(16) float cnLDS[2048];       // 8 KB

  const int t = threadIdx.x;
  const int w = t >> 6;
  const int l = t & 63;
  const int h = blockIdx.x & 1;
  const int row0 = (blockIdx.x >> 1) * 256;

  for (int i = t * 4; i < 2048; i += 1024)
    *(float4*)&cnLDS[i] = *(const float4*)&cnorm[h * 2048 + i];

  // x fragments hi/lo -> registers. Wave w owns rows row0+w*64+tt*32+(l&31).
  v8s xhi[2][8], xlo[2][8];
#pragma unroll
  for (int tt = 0; tt < 2; ++tt) {
#pragma unroll
    for (int ks = 0; ks < 8; ++ks) {
      int xrow = row0 + w * 64 + tt * 32 + (l & 31);
      int kb = ks * 16 + (l >> 5) * 8;
      const float* xp = x + (size_t)xrow * Dn + kb;
      float4 a = ((const float4*)xp)[0];
      float4 b = ((const float4*)xp)[1];
      float v[8] = {a.x, a.y, a.z, a.w, b.x, b.y, b.z, b.w};
      v8s hi, lo;
#pragma unroll
      for (int j = 0; j < 8; ++j) {
        unsigned short hh = bf16_rne(v[j]);
        hi[j] = (short)hh;
        lo[j] = (short)bf16_rne(v[j] - bf16_to_f32(hh));
      }
      xhi[tt][ks] = hi;
      xlo[tt][ks] = lo;
    }
  }

  const char* packbase =
      (const char*)pack + (size_t)(h * 64) * 16384 + w * 1024 + l * 16;
  auto stage = [&](int ct, int bufi) {
    const char* src = packbase + (size_t)ct * 16384;
    char* dst = (char*)&packLDS[bufi][0] + w * 1024;  // wave-uniform base
#pragma unroll
    for (int i = 0; i < 4; ++i) {
      __builtin_amdgcn_global_load_lds(
          (const __attribute__((address_space(1))) unsigned*)(src + i * 4096),
          (__attribute__((address_space(3))) unsigned*)(dst + i * 4096), 16, 0,
          0);
    }
  };

  stage(0, 0);
  __syncthreads();

  float min1[2] = {3.4e38f, 3.4e38f};
  float min2[2] = {3.4e38f, 3.4e38f};
  int idx[2] = {0, 0};

  v16f accA0, accA1, accB0, accB1;

  auto mfma_tile = [&](v16f& c0, v16f& c1, int buf) {
#pragma unroll
    for (int i = 0; i < 16; ++i) {
      c0[i] = 0.f;
      c1[i] = 0.f;
    }
#pragma unroll
    for (int ks = 0; ks < 8; ++ks) {
      const short* pb = &packLDS[buf][ks * 1024 + l * 8];
      v8s a_h = *(const v8s*)pb;
      v8s a_l = *(const v8s*)(pb + 512);
      c0 = MFMA(a_h, xhi[0][ks], c0);
      c1 = MFMA(a_h, xhi[1][ks], c1);
      c0 = MFMA(a_h, xlo[0][ks], c0);
      c1 = MFMA(a_h, xlo[1][ks], c1);
      c0 = MFMA(a_l, xhi[0][ks], c0);
      c1 = MFMA(a_l, xhi[1][ks], c1);
    }
  };

  auto epilogue = [&](const v16f& c0, const v16f& c1, int it) {
    const int lbase = it * 32 + 4 * (l >> 5);
    float4 cn4[4];
#pragma unroll
    for (int g = 0; g < 4; ++g)
      cn4[g] = *(const float4*)&cnLDS[lbase + 8 * g];
#pragma unroll
    for (int r = 0; r < 16; ++r) {
      const int g = r >> 2, wi = r & 3;
      const int code = h * 2048 + lbase + 8 * g + wi;
      const float cn = ((const float*)&cn4[g])[wi];
      float k0 = fmaf(-2.f, c0[r], cn);
      bool lt0 = k0 < min1[0];
      min2[0] = lt0 ? min1[0] : fminf(min2[0], k0);
      idx[0] = lt0 ? code : idx[0];
      min1[0] = lt0 ? k0 : min1[0];
      float k1 = fmaf(-2.f, c1[r], cn);
      bool lt1 = k1 < min1[1];
      min2[1] = lt1 ? min1[1] : fminf(min2[1], k1);
      idx[1] = lt1 ? code : idx[1];
      min1[1] = lt1 ? k1 : min1[1];
    }
  };

  for (int ith = 0; ith < 32; ++ith) {
    const int itE = 2 * ith;  // even tile -> buf 0, accs A
    if (itE + 1 < 64) stage(itE + 1, 1);
    mfma_tile(accA0, accA1, 0);
    if (ith > 0) epilogue(accB0, accB1, itE - 1);
    __syncthreads();

    const int itO = itE + 1;  // odd tile -> buf 1, accs B
    if (itO + 1 < 64) stage(itO + 1, 0);
    mfma_tile(accB0, accB1, 1);
    epilogue(accA0, accA1, itE);
    __syncthreads();
  }
  epilogue(accB0, accB1, 63);

  // Merge lane pair (l, l^32): same x-row, complementary code rows.
#pragma unroll
  for (int tt = 0; tt < 2; ++tt) {
    float o1 = __shfl_xor(min1[tt], 32);
    float o2 = __shfl_xor(min2[tt], 32);
    int oi = __shfl_xor(idx[tt], 32);
    bool sw = (o1 < min1[tt]) || (o1 == min1[tt] && oi < idx[tt]);
    float n1 = sw ? o1 : min1[tt];
    int ni = sw ? oi : idx[tt];
    float big = sw ? min1[tt] : o1;
    float n2 = fminf(fminf(min2[tt], o2), big);
    if (l < 32) {
      int row = row0 + w * 64 + tt * 32 + l;
      pm1[h * Bn + row] = n1;
      pm2[h * Bn + row] = n2;
      pidx[h * Bn + row] = (float)ni;
    }
  }
}

// ---------------------------------------------------------------------------
// Merge the two code-half partials; write idxf; flag small-margin rows.
// ---------------------------------------------------------------------------
__global__ void merge_kernel(const float* __restrict__ pm1,
                             const float* __restrict__ pm2,
                             const float* __restrict__ pidx,
                             float* __restrict__ idxf,
                             int* __restrict__ flaglist,
                             int* __restrict__ flagcount) {
  int r = blockIdx.x * 256 + threadIdx.x;
  float a1 = pm1[r], b1 = pm1[Bn + r];
  float a2 = pm2[r], b2 = pm2[Bn + r];
  float ai = pidx[r], bi = pidx[Bn + r];
  bool a = (a1 <= b1);
  float m1 = a ? a1 : b1;
  float mi = a ? ai : bi;
  float m2 = a ? fminf(a2, b1) : fminf(b2, a1);
  idxf[r] = mi;
  if (m2 - m1 < TAU) {
    int p = atomicAdd(flagcount, 1);
    flaglist[p] = r;
  }
}

// ---------------------------------------------------------------------------
// Exact fp32 rescore of flagged rows (grid-stride block-per-row).
// ---------------------------------------------------------------------------
__global__ void rescore_kernel(const float* __restrict__ x,
                               const float* __restrict__ codes,
                               const float* __restrict__ cnorm,
                               const int* __restrict__ flaglist,
                               const int* __restrict__ flagcount,
                               float* __restrict__ idxf) {
  __shared__ __align__(16) float xrow[Dn];
  __shared__ float rv[256];
  __shared__ int ri[256];
  const int t = threadIdx.x;
  const int cnt = *flagcount;

  for (int j = blockIdx.x; j < cnt; j += gridDim.x) {
    const int r = flaglist[j];
    __syncthreads();
    if (t < 32) ((float4*)xrow)[t] = ((const float4*)(x + (size_t)r * Dn))[t];
    __syncthreads();
    float bv = 3.4e38f;
    int bi = 0x7fffffff;
    for (int c = t; c < Cn; c += 256) {
      const float4* cp = (const float4*)(codes + (size_t)c * Dn);
      float s = 0.f;
#pragma unroll
      for (int i = 0; i < Dn / 4; ++i) {
        float4 v = cp[i];
        float4 u = ((const float4*)xrow)[i];
        s = fmaf(v.x, u.x, s);
        s = fmaf(v.y, u.y, s);
        s = fmaf(v.z, u.z, s);
        s = fmaf(v.w, u.w, s);
      }
      float key = fmaf(-2.f, s, cnorm[c]);
      if (key < bv) { bv = key; bi = c; }
    }
    rv[t] = bv;
    ri[t] = bi;
    __syncthreads();
    for (int off = 128; off > 0; off >>= 1) {
      if (t < off) {
        float ov = rv[t + off];
        int oi = ri[t + off];
        if (ov < rv[t] || (ov == rv[t] && oi < ri[t])) {
          rv[t] = ov;
          ri[t] = oi;
        }
      }
      __syncthreads();
    }
    if (t == 0) idxf[r] = (float)ri[0];
  }
}

// ---------------------------------------------------------------------------
// Gather + loss. 512 blocks x 128 rows; ONE global atomic per block
// (was 8192 same-address atomics -> serialized ~150 us).
// ---------------------------------------------------------------------------
__global__ void gather_loss_kernel(const float* __restrict__ x,
                                   const float* __restrict__ codes,
                                   const float* __restrict__ idxf,
                                   float* __restrict__ quant,
                                   float* __restrict__ loss) {
  __shared__ float part[8];
  const int t = threadIdx.x;
  const int wave = t >> 6;
  const int lane = t & 63;
  const int half = lane >> 5;
  const int l = lane & 31;
  const int base = blockIdx.x * 128;

  float s = 0.f;
#pragma unroll 4
  for (int pass = 0; pass < 16; ++pass) {
    int row = base + pass * 8 + (wave << 1) + half;
    int idx = (int)idxf[row];
    float4 cv = ((const float4*)(codes + (size_t)idx * Dn))[l];
    float4 xv = ((const float4*)(x + (size_t)row * Dn))[l];
    ((float4*)(quant + (size_t)row * Dn))[l] = cv;
    float d0 = xv.x - cv.x, d1 = xv.y - cv.y, d2 = xv.z - cv.z,
          d3 = xv.w - cv.w;
    s += d0 * d0 + d1 * d1 + d2 * d2 + d3 * d3;
  }
#pragma unroll
  for (int off = 16; off > 0; off >>= 1) s += __shfl_down(s, off, 32);
  if (l == 0) part[(wave << 1) + half] = s;
  __syncthreads();
  if (t == 0) {
    float tot = 0.f;
#pragma unroll
    for (int i = 0; i < 8; ++i) tot += part[i];
    atomicAdd(loss, tot * (1.25f / 65536.f));
  }
}

// ---------------------------------------------------------------------------
extern "C" void kernel_launch(void* const* d_in, const int* in_sizes, int n_in,
                              void* d_out, int out_size, void* d_ws,
                              size_t ws_size, hipStream_t stream) {
  const float* x = (const float*)d_in[0];
  const float* codes = (const float*)d_in[1];

  float* quant = (float*)d_out;            // B*D floats (scratch until gather)
  float* idxf = quant + (size_t)Bn * Dn;   // B floats
  float* loss = idxf + Bn;                 // 1 float
  float* cnorm = (float*)d_ws;             // 16 KB

  short* pack = (short*)quant;                 // 2 MB @ 0
  int* flagcount = (int*)(quant + (1 << 20));  // @ 4 MB
  int* flaglist = flagcount + 1;
  float* pm1 = quant + (2 << 20);              // @ 8 MB
  float* pm2 = pm1 + 2 * Bn;
  float* pidx = pm2 + 2 * Bn;

  cnorm_kernel<<<Cn / 256, 256, 0, stream>>>(codes, cnorm, loss, flagcount);
  pack_codes_kernel<<<256, 256, 0, stream>>>(codes, pack);
  argmin_mfma_kernel<<<512, 256, 0, stream>>>(x, pack, cnorm, pm1, pm2, pidx);
  merge_kernel<<<Bn / 256, 256, 0, stream>>>(pm1, pm2, pidx, idxf, flaglist,
                                             flagcount);
  rescore_kernel<<<256, 256, 0, stream>>>(x, codes, cnorm, flaglist, flagcount,
                                          idxf);
  gather_loss_kernel<<<Bn / 128, 256, 0, stream>>>(x, codes, idxf, quant,
                                                   loss);
}

// Round 6
// 382.725 us; speedup vs baseline: 3.1209x; 1.0014x over previous
//
#include <hip/hip_runtime.h>

constexpr int Bn = 65536;
constexpr int Cn = 4096;
constexpr int Dn = 128;
constexpr float TAU = 1e-3f;  // key error ~3e-5; 30x guard band

typedef short v8s __attribute__((ext_vector_type(8)));
typedef float v16f __attribute__((ext_vector_type(16)));

#define MFMA(a, b, c) __builtin_amdgcn_mfma_f32_32x32x16_bf16((a), (b), (c), 0, 0, 0)

__device__ __forceinline__ unsigned short bf16_rne(float f) {
  unsigned u = __float_as_uint(f);
  return (unsigned short)((u + 0x7fffu + ((u >> 16) & 1u)) >> 16);
}
__device__ __forceinline__ float bf16_to_f32(unsigned short h) {
  return __uint_as_float(((unsigned)h) << 16);
}

// ---------------------------------------------------------------------------
// cnorm (fp64 accum) + zero loss + zero flag counter
// ---------------------------------------------------------------------------
__global__ void cnorm_kernel(const float* __restrict__ codes,
                             float* __restrict__ cnorm,
                             float* __restrict__ loss,
                             int* __restrict__ flagcount) {
  int n = blockIdx.x * blockDim.x + threadIdx.x;
  if (blockIdx.x == 0 && threadIdx.x == 0) {
    *loss = 0.f;
    *flagcount = 0;
  }
  if (n >= Cn) return;
  const float4* p = (const float4*)(codes + (size_t)n * Dn);
  double s = 0.0;
#pragma unroll
  for (int i = 0; i < Dn / 4; ++i) {
    float4 v = p[i];
    s += (double)v.x * v.x + (double)v.y * v.y + (double)v.z * v.z +
         (double)v.w * v.w;
  }
  cnorm[n] = (float)s;
}

// ---------------------------------------------------------------------------
// Pack codes, MFMA A-fragment order, hi/lo bf16 planes, PRE-SCALED BY -2.
// Tile ct (128 tiles, 9216 shorts = 18432 B each):
//   slice s in [0,8): hi @ ct*9216 + s*1024 + l*8, lo @ +512
//   slice 8: cnorm fragment (lanes l<32: j=0,1,2 hold cnorm hi/mid/lo bf16
//            split of code 32*ct+(l&31)); rest zeros. With B=ones at k=0..2,
//            one MFMA adds cnorm[code] to every row: acc becomes the key
//            cnorm - 2*dot directly.
// ---------------------------------------------------------------------------
__global__ void pack_codes_kernel(const float* __restrict__ codes,
                                  const float* __restrict__ cnorm,
                                  short* __restrict__ pack) {
  int tid = blockIdx.x * 256 + threadIdx.x;  // 288 blocks -> 1152 wave-frags
  int f = tid >> 6;
  int l = tid & 63;
  int ct = f / 9, s = f % 9;
  int code = (ct << 5) + (l & 31);
  if (s < 8) {
    int kb = (s << 4) + ((l >> 5) << 3);
    const float* p = codes + (size_t)code * Dn + kb;
    float4 a = ((const float4*)p)[0];
    float4 b = ((const float4*)p)[1];
    float v[8] = {a.x, a.y, a.z, a.w, b.x, b.y, b.z, b.w};
    v8s hi, lo;
#pragma unroll
    for (int j = 0; j < 8; ++j) {
      float sv = -2.f * v[j];  // exact scale
      unsigned short h = bf16_rne(sv);
      hi[j] = (short)h;
      lo[j] = (short)bf16_rne(sv - bf16_to_f32(h));
    }
    *(v8s*)(pack + (size_t)ct * 9216 + s * 1024 + l * 8) = hi;
    *(v8s*)(pack + (size_t)ct * 9216 + s * 1024 + 512 + l * 8) = lo;
  } else {
    v8s a = {0, 0, 0, 0, 0, 0, 0, 0};
    if (l < 32) {
      float cn = cnorm[code];
      unsigned short h1 = bf16_rne(cn);
      float r1 = cn - bf16_to_f32(h1);
      unsigned short h2 = bf16_rne(r1);
      float r2 = r1 - bf16_to_f32(h2);
      unsigned short h3 = bf16_rne(r2);
      a[0] = (short)h1;
      a[1] = (short)h2;
      a[2] = (short)h3;
    }
    v8s z = {0, 0, 0, 0, 0, 0, 0, 0};
    *(v8s*)(pack + (size_t)ct * 9216 + 8 * 1024 + l * 8) = a;
    *(v8s*)(pack + (size_t)ct * 9216 + 8 * 1024 + 512 + l * 8) = z;
  }
}

// ---------------------------------------------------------------------------
// Main: LDS-staged code-split sweep (R4/R5 structure), epilogue in MFMA
// domain. Per tile per acc: 1 cnorm-MFMA (C = persistent zero) + 24 hi/lo
// MFMAs; acc[r] = key. Epilogue = min3-tree + rare masked index extraction.
// C/D 32x32: col = lane&31 = x-row, code-row = (r&3)+8*(r>>2)+4*(lane>>5).
// ---------------------------------------------------------------------------
__launch_bounds__(256, 2)
__global__ void argmin_mfma_kernel(const float* __restrict__ x,
                                   const short* __restrict__ pack,
                                   float* __restrict__ pm1,
                                   float* __restrict__ pm2,
                                   float* __restrict__ pidx) {
  __shared__ __align__(16) short packLDS[2][9216];  // 2 x 18 KB

  const int t = threadIdx.x;
  const int w = t >> 6;
  const int l = t & 63;
  const int h = blockIdx.x & 1;
  const int row0 = (blockIdx.x >> 1) * 256;

  // x fragments hi/lo -> registers. Wave w owns rows row0+w*64+tt*32+(l&31).
  v8s xhi[2][8], xlo[2][8];
#pragma unroll
  for (int tt = 0; tt < 2; ++tt) {
#pragma unroll
    for (int ks = 0; ks < 8; ++ks) {
      int xrow = row0 + w * 64 + tt * 32 + (l & 31);
      int kb = ks * 16 + (l >> 5) * 8;
      const float* xp = x + (size_t)xrow * Dn + kb;
      float4 a = ((const float4*)xp)[0];
      float4 b = ((const float4*)xp)[1];
      float v[8] = {a.x, a.y, a.z, a.w, b.x, b.y, b.z, b.w};
      v8s hi, lo;
#pragma unroll
      for (int j = 0; j < 8; ++j) {
        unsigned short hh = bf16_rne(v[j]);
        hi[j] = (short)hh;
        lo[j] = (short)bf16_rne(v[j] - bf16_to_f32(hh));
      }
      xhi[tt][ks] = hi;
      xlo[tt][ks] = lo;
    }
  }

  // B fragment of ones at k=0,1,2 (pairs with the cnorm A-slice).
  v8s bones;
#pragma unroll
  for (int j = 0; j < 8; ++j)
    bones[j] = (l < 32 && j < 3) ? (short)0x3F80 : (short)0;

  v16f zacc;
#pragma unroll
  for (int i = 0; i < 16; ++i) zacc[i] = 0.f;

  const char* packbase = (const char*)pack + (size_t)(h * 64) * 18432;
  auto stage = [&](int ct, int bufi) {
    const char* src = packbase + (size_t)ct * 18432 + l * 16;
    char* dstb = (char*)&packLDS[bufi][0];
    for (int i = w; i < 18; i += 4) {  // 18 KB = 18 wave-issues of 1 KB
      __builtin_amdgcn_global_load_lds(
          (const __attribute__((address_space(1))) unsigned*)(src + i * 1024),
          (__attribute__((address_space(3))) unsigned*)(dstb + i * 1024), 16,
          0, 0);
    }
  };

  stage(0, 0);
  __syncthreads();

  float min1[2] = {3.4e38f, 3.4e38f};
  float min2[2] = {3.4e38f, 3.4e38f};
  int idx[2] = {0, 0};

  auto update = [&](const v16f& a, int tt, int codebase) {
    float g0 = fminf(fminf(a[0], a[1]), a[2]);
    float g1 = fminf(fminf(a[3], a[4]), a[5]);
    float g2 = fminf(fminf(a[6], a[7]), a[8]);
    float g3 = fminf(fminf(a[9], a[10]), a[11]);
    float g4 = fminf(fminf(a[12], a[13]), a[14]);
    float tmin = fminf(fminf(fminf(g0, g1), g2), fminf(fminf(g3, g4), a[15]));
    float m2cand = fminf(min2[tt], tmin);
    bool upd = tmin < min1[tt];
    if (upd) {  // divergent-rare: index + exact tile-2nd extraction
      int rsel = 15;
#pragma unroll
      for (int r = 14; r >= 0; --r) rsel = (a[r] == tmin) ? r : rsel;
      float u[16];
#pragma unroll
      for (int r = 0; r < 16; ++r) u[r] = (r == rsel) ? 3.4e38f : a[r];
      float q0 = fminf(fminf(u[0], u[1]), u[2]);
      float q1 = fminf(fminf(u[3], u[4]), u[5]);
      float q2 = fminf(fminf(u[6], u[7]), u[8]);
      float q3 = fminf(fminf(u[9], u[10]), u[11]);
      float q4 = fminf(fminf(u[12], u[13]), u[14]);
      float t2nd =
          fminf(fminf(fminf(q0, q1), q2), fminf(fminf(q3, q4), u[15]));
      min2[tt] = fminf(fminf(min2[tt], min1[tt]), t2nd);
      min1[tt] = tmin;
      idx[tt] = codebase + 8 * (rsel >> 2) + (rsel & 3);
    } else {
      min2[tt] = m2cand;
    }
  };

  for (int it = 0; it < 64; ++it) {
    const int buf = it & 1;
    if (it + 1 < 64) stage(it + 1, buf ^ 1);

    const short* base = &packLDS[buf][l * 8];
    v8s a_cn = *(const v8s*)(base + 8 * 1024);
    v16f acc0 = MFMA(a_cn, bones, zacc);  // acc = cnorm[code], no zero-init
    v16f acc1 = MFMA(a_cn, bones, zacc);
#pragma unroll
    for (int s = 0; s < 8; ++s) {
      v8s a_h = *(const v8s*)(base + s * 1024);
      v8s a_l = *(const v8s*)(base + s * 1024 + 512);
      acc0 = MFMA(a_h, xhi[0][s], acc0);
      acc1 = MFMA(a_h, xhi[1][s], acc1);
      acc0 = MFMA(a_h, xlo[0][s], acc0);
      acc1 = MFMA(a_h, xlo[1][s], acc1);
      acc0 = MFMA(a_l, xhi[0][s], acc0);
      acc1 = MFMA(a_l, xhi[1][s], acc1);
    }

    const int codebase = h * 2048 + it * 32 + 4 * (l >> 5);
    update(acc0, 0, codebase);
    update(acc1, 1, codebase);
    __syncthreads();
  }

  // Merge lane pair (l, l^32): same x-row, complementary code rows.
#pragma unroll
  for (int tt = 0; tt < 2; ++tt) {
    float o1 = __shfl_xor(min1[tt], 32);
    float o2 = __shfl_xor(min2[tt], 32);
    int oi = __shfl_xor(idx[tt], 32);
    bool sw = (o1 < min1[tt]) || (o1 == min1[tt] && oi < idx[tt]);
    float n1 = sw ? o1 : min1[tt];
    int ni = sw ? oi : idx[tt];
    float big = sw ? min1[tt] : o1;
    float n2 = fminf(fminf(min2[tt], o2), big);
    if (l < 32) {
      int row = row0 + w * 64 + tt * 32 + l;
      pm1[h * Bn + row] = n1;
      pm2[h * Bn + row] = n2;
      pidx[h * Bn + row] = (float)ni;
    }
  }
}

// ---------------------------------------------------------------------------
// Merge the two code-half partials; write idxf; flag small-margin rows.
// ---------------------------------------------------------------------------
__global__ void merge_kernel(const float* __restrict__ pm1,
                             const float* __restrict__ pm2,
                             const float* __restrict__ pidx,
                             float* __restrict__ idxf,
                             int* __restrict__ flaglist,
                             int* __restrict__ flagcount) {
  int r = blockIdx.x * 256 + threadIdx.x;
  float a1 = pm1[r], b1 = pm1[Bn + r];
  float a2 = pm2[r], b2 = pm2[Bn + r];
  float ai = pidx[r], bi = pidx[Bn + r];
  bool a = (a1 <= b1);
  float m1 = a ? a1 : b1;
  float mi = a ? ai : bi;
  float m2 = a ? fminf(a2, b1) : fminf(b2, a1);
  idxf[r] = mi;
  if (m2 - m1 < TAU) {
    int p = atomicAdd(flagcount, 1);
    flaglist[p] = r;
  }
}

// ---------------------------------------------------------------------------
// Exact fp32 rescore of flagged rows (grid-stride block-per-row).
// ---------------------------------------------------------------------------
__global__ void rescore_kernel(const float* __restrict__ x,
                               const float* __restrict__ codes,
                               const float* __restrict__ cnorm,
                               const int* __restrict__ flaglist,
                               const int* __restrict__ flagcount,
                               float* __restrict__ idxf) {
  __shared__ __align__(16) float xrow[Dn];
  __shared__ float rv[256];
  __shared__ int ri[256];
  const int t = threadIdx.x;
  const int cnt = *flagcount;

  for (int j = blockIdx.x; j < cnt; j += gridDim.x) {
    const int r = flaglist[j];
    __syncthreads();
    if (t < 32) ((float4*)xrow)[t] = ((const float4*)(x + (size_t)r * Dn))[t];
    __syncthreads();
    float bv = 3.4e38f;
    int bi = 0x7fffffff;
    for (int c = t; c < Cn; c += 256) {
      const float4* cp = (const float4*)(codes + (size_t)c * Dn);
      float s = 0.f;
#pragma unroll
      for (int i = 0; i < Dn / 4; ++i) {
        float4 v = cp[i];
        float4 u = ((const float4*)xrow)[i];
        s = fmaf(v.x, u.x, s);
        s = fmaf(v.y, u.y, s);
        s = fmaf(v.z, u.z, s);
        s = fmaf(v.w, u.w, s);
      }
      float key = fmaf(-2.f, s, cnorm[c]);
      if (key < bv) { bv = key; bi = c; }
    }
    rv[t] = bv;
    ri[t] = bi;
    __syncthreads();
    for (int off = 128; off > 0; off >>= 1) {
      if (t < off) {
        float ov = rv[t + off];
        int oi = ri[t + off];
        if (ov < rv[t] || (ov == rv[t] && oi < ri[t])) {
          rv[t] = ov;
          ri[t] = oi;
        }
      }
      __syncthreads();
    }
    if (t == 0) idxf[r] = (float)ri[0];
  }
}

// ---------------------------------------------------------------------------
// Gather + loss. 2048 blocks x 32 rows (more latency-hiding parallelism);
// one global atomic per block.
// ---------------------------------------------------------------------------
__global__ void gather_loss_kernel(const float* __restrict__ x,
                                   const float* __restrict__ codes,
                                   const float* __restrict__ idxf,
                                   float* __restrict__ quant,
                                   float* __restrict__ loss) {
  __shared__ float part[8];
  const int t = threadIdx.x;
  const int wave = t >> 6;
  const int lane = t & 63;
  const int half = lane >> 5;
  const int l = lane & 31;
  const int base = blockIdx.x * 32;

  float s = 0.f;
#pragma unroll
  for (int pass = 0; pass < 4; ++pass) {
    int row = base + pass * 8 + (wave << 1) + half;
    int idx = (int)idxf[row];
    float4 cv = ((const float4*)(codes + (size_t)idx * Dn))[l];
    float4 xv = ((const float4*)(x + (size_t)row * Dn))[l];
    ((float4*)(quant + (size_t)row * Dn))[l] = cv;
    float d0 = xv.x - cv.x, d1 = xv.y - cv.y, d2 = xv.z - cv.z,
          d3 = xv.w - cv.w;
    s += d0 * d0 + d1 * d1 + d2 * d2 + d3 * d3;
  }
#pragma unroll
  for (int off = 16; off > 0; off >>= 1) s += __shfl_down(s, off, 32);
  if (l == 0) part[(wave << 1) + half] = s;
  __syncthreads();
  if (t == 0) {
    float tot = 0.f;
#pragma unroll
    for (int i = 0; i < 8; ++i) tot += part[i];
    atomicAdd(loss, tot * (1.25f / 65536.f));
  }
}

// ---------------------------------------------------------------------------
extern "C" void kernel_launch(void* const* d_in, const int* in_sizes, int n_in,
                              void* d_out, int out_size, void* d_ws,
                              size_t ws_size, hipStream_t stream) {
  const float* x = (const float*)d_in[0];
  const float* codes = (const float*)d_in[1];

  float* quant = (float*)d_out;            // B*D floats (scratch until gather)
  float* idxf = quant + (size_t)Bn * Dn;   // B floats
  float* loss = idxf + Bn;                 // 1 float
  float* cnorm = (float*)d_ws;             // 16 KB

  short* pack = (short*)quant;                 // 2.25 MB @ 0
  int* flagcount = (int*)(quant + (1 << 20));  // @ 4 MB
  int* flaglist = flagcount + 1;               // up to 256 KB
  float* pm1 = quant + (2 << 20);              // @ 8 MB
  float* pm2 = pm1 + 2 * Bn;
  float* pidx = pm2 + 2 * Bn;

  cnorm_kernel<<<Cn / 256, 256, 0, stream>>>(codes, cnorm, loss, flagcount);
  pack_codes_kernel<<<288, 256, 0, stream>>>(codes, cnorm, pack);
  argmin_mfma_kernel<<<512, 256, 0, stream>>>(x, pack, pm1, pm2, pidx);
  merge_kernel<<<Bn / 256, 256, 0, stream>>>(pm1, pm2, pidx, idxf, flaglist,
                                             flagcount);
  rescore_kernel<<<256, 256, 0, stream>>>(x, codes, cnorm, flaglist, flagcount,
                                          idxf);
  gather_loss_kernel<<<Bn / 32, 256, 0, stream>>>(x, codes, idxf, quant, loss);
}

// Round 7
// 371.608 us; speedup vs baseline: 3.2142x; 1.0299x over previous
//
#include <hip/hip_runtime.h>

constexpr int Bn = 65536;
constexpr int Cn = 4096;
constexpr int Dn = 128;
constexpr float TAU = 0.03f;  // key err std ~3.4e-3 (f16 x); 6-sigma pairwise guard

typedef _Float16 v8h __attribute__((ext_vector_type(8)));
typedef float v16f __attribute__((ext_vector_type(16)));

#define MFMA16(a, b, c) __builtin_amdgcn_mfma_f32_32x32x16_f16((a), (b), (c), 0, 0, 0)

// ---------------------------------------------------------------------------
// Pack codes into MFMA A-fragment order as 2-term f16 planes, PRE-SCALED -2.
// Also computes cnorm (fp64) inline and zeroes flagcount.
// Tile ct (128 tiles, 9216 halves = 18432 B):
//   slice s in [0,8): hi @ ct*9216 + s*1024 + l*8, lo @ +512
//   slice 8: 3-term f16 split of (cnorm[code] + 512) at k=0,1,2 (lanes l<32);
//            with B=ones at k=0..2 one MFMA makes acc = key+512 directly
//            (+512 keeps keys positive => u32-sortable floats).
// ---------------------------------------------------------------------------
__global__ void pack_codes_kernel(const float* __restrict__ codes,
                                  float* __restrict__ cnorm,
                                  _Float16* __restrict__ pack,
                                  int* __restrict__ flagcount) {
  int tid = blockIdx.x * 256 + threadIdx.x;  // 288 blocks -> 1152 wave-frags
  if (tid == 0) *flagcount = 0;
  int f = tid >> 6;
  int l = tid & 63;
  int ct = f / 9, s = f % 9;
  int code = (ct << 5) + (l & 31);
  if (s < 8) {
    int kb = (s << 4) + ((l >> 5) << 3);
    const float* p = codes + (size_t)code * Dn + kb;
    float4 a = ((const float4*)p)[0];
    float4 b = ((const float4*)p)[1];
    float v[8] = {a.x, a.y, a.z, a.w, b.x, b.y, b.z, b.w};
    v8h hi, lo;
#pragma unroll
    for (int j = 0; j < 8; ++j) {
      float sv = -2.f * v[j];  // exact scale
      _Float16 h = (_Float16)sv;
      hi[j] = h;
      lo[j] = (_Float16)(sv - (float)h);
    }
    *(v8h*)(pack + (size_t)ct * 9216 + s * 1024 + l * 8) = hi;
    *(v8h*)(pack + (size_t)ct * 9216 + s * 1024 + 512 + l * 8) = lo;
  } else {
    v8h a = {0, 0, 0, 0, 0, 0, 0, 0};
    if (l < 32) {
      const float4* p = (const float4*)(codes + (size_t)code * Dn);
      double sd = 0.0;
#pragma unroll
      for (int i = 0; i < Dn / 4; ++i) {
        float4 v = p[i];
        sd += (double)v.x * v.x + (double)v.y * v.y + (double)v.z * v.z +
              (double)v.w * v.w;
      }
      float cn = (float)sd;
      cnorm[code] = cn;
      float c5 = cn + 512.f;
      _Float16 h1 = (_Float16)c5;
      float r1 = c5 - (float)h1;
      _Float16 h2 = (_Float16)r1;
      float r2 = r1 - (float)h2;
      _Float16 h3 = (_Float16)r2;
      a[0] = h1;
      a[1] = h2;
      a[2] = h3;
    }
    v8h z = {0, 0, 0, 0, 0, 0, 0, 0};
    *(v8h*)(pack + (size_t)ct * 9216 + 8 * 1024 + l * 8) = a;
    *(v8h*)(pack + (size_t)ct * 9216 + 8 * 1024 + 512 + l * 8) = z;
  }
}

// ---------------------------------------------------------------------------
// Main: LDS-staged code-split sweep (proven structure). Per tile per wave:
// 17 ds_read_b128 -> 34 MFMA (2 f16 product terms x 2 accs x 8 ks + 2 cnorm).
// acc[r] = key + 512 (always positive). Branchless epilogue: pack 4-bit r
// into low mantissa bits, v_min_u32 trees for (min, exact in-tile 2nd, idx).
// C/D 32x32: col = lane&31 = x-row, code-row = (r&3)+8*(r>>2)+4*(lane>>5).
// ---------------------------------------------------------------------------
__launch_bounds__(256, 2)
__global__ void argmin_mfma_kernel(const float* __restrict__ x,
                                   const _Float16* __restrict__ pack,
                                   float* __restrict__ pm1,
                                   float* __restrict__ pm2,
                                   float* __restrict__ pidx) {
  __shared__ __align__(16) _Float16 packLDS[2][9216];  // 2 x 18 KB

  const int t = threadIdx.x;
  const int w = t >> 6;
  const int l = t & 63;
  const int h = blockIdx.x & 1;
  const int row0 = (blockIdx.x >> 1) * 256;

  // x fragments -> registers (single f16). Wave w: rows row0+w*64+tt*32+(l&31).
  v8h xh[2][8];
#pragma unroll
  for (int tt = 0; tt < 2; ++tt) {
#pragma unroll
    for (int ks = 0; ks < 8; ++ks) {
      int xrow = row0 + w * 64 + tt * 32 + (l & 31);
      int kb = ks * 16 + (l >> 5) * 8;
      const float* xp = x + (size_t)xrow * Dn + kb;
      float4 a = ((const float4*)xp)[0];
      float4 b = ((const float4*)xp)[1];
      float v[8] = {a.x, a.y, a.z, a.w, b.x, b.y, b.z, b.w};
      v8h hh;
#pragma unroll
      for (int j = 0; j < 8; ++j) hh[j] = (_Float16)v[j];
      xh[tt][ks] = hh;
    }
  }

  // B fragment of f16 ones at k=0,1,2 (pairs with the cnorm A-slice).
  v8h bones;
#pragma unroll
  for (int j = 0; j < 8; ++j)
    bones[j] = (l < 32 && j < 3) ? (_Float16)1.0f : (_Float16)0.0f;

  v16f zacc;
#pragma unroll
  for (int i = 0; i < 16; ++i) zacc[i] = 0.f;

  const char* packbase = (const char*)pack + (size_t)(h * 64) * 18432;
  auto stage = [&](int ct, int bufi) {
    const char* src = packbase + (size_t)ct * 18432 + l * 16;
    char* dstb = (char*)&packLDS[bufi][0];
    for (int i = w; i < 18; i += 4) {
      __builtin_amdgcn_global_load_lds(
          (const __attribute__((address_space(1))) unsigned*)(src + i * 1024),
          (__attribute__((address_space(3))) unsigned*)(dstb + i * 1024), 16,
          0, 0);
    }
  };

  stage(0, 0);
  __syncthreads();

  float min1[2] = {3.4e38f, 3.4e38f};
  float min2[2] = {3.4e38f, 3.4e38f};
  int idx[2] = {0, 0};

  auto update = [&](const v16f& a, int tt, int codebase) {
    // pack r into low 4 mantissa bits (keys positive => u32 order = f32 order)
    unsigned b[16];
#pragma unroll
    for (int r = 0; r < 16; ++r)
      b[r] = (__float_as_uint(a[r]) & 0xFFFFFFF0u) | (unsigned)r;
    // tree1: min + index
    unsigned m0 = min(min(min(b[0], b[1]), min(b[2], b[3])),
                      min(min(b[4], b[5]), min(b[6], b[7])));
    unsigned m1 = min(min(min(b[8], b[9]), min(b[10], b[11])),
                      min(min(b[12], b[13]), min(b[14], b[15])));
    unsigned u1 = min(m0, m1);
    // mask winner (packed values unique by r), tree2: exact in-tile 2nd
    unsigned c[16];
#pragma unroll
    for (int r = 0; r < 16; ++r) c[r] = (b[r] == u1) ? 0xFFFFFFFFu : b[r];
    unsigned n0 = min(min(min(c[0], c[1]), min(c[2], c[3])),
                      min(min(c[4], c[5]), min(c[6], c[7])));
    unsigned n1 = min(min(min(c[8], c[9]), min(c[10], c[11])),
                      min(min(c[12], c[13]), min(c[14], c[15])));
    unsigned u2 = min(n0, n1);

    float t1 = __uint_as_float(u1 & 0xFFFFFFF0u);
    float t2 = __uint_as_float(u2 & 0xFFFFFFF0u);
    unsigned r1 = u1 & 15u;
    int tidx = codebase + (int)(8 * (r1 >> 2) + (r1 & 3));
    bool lt = t1 < min1[tt];
    min2[tt] = lt ? fminf(min1[tt], t2) : fminf(min2[tt], t1);
    idx[tt] = lt ? tidx : idx[tt];
    min1[tt] = lt ? t1 : min1[tt];
  };

  for (int it = 0; it < 64; ++it) {
    const int buf = it & 1;
    if (it + 1 < 64) stage(it + 1, buf ^ 1);

    const _Float16* base = &packLDS[buf][l * 8];
    v8h a_cn = *(const v8h*)(base + 8 * 1024);
    v16f acc0 = MFMA16(a_cn, bones, zacc);  // acc = cnorm+512
    v16f acc1 = MFMA16(a_cn, bones, zacc);
#pragma unroll
    for (int s = 0; s < 8; ++s) {
      v8h a_h = *(const v8h*)(base + s * 1024);
      v8h a_l = *(const v8h*)(base + s * 1024 + 512);
      acc0 = MFMA16(a_h, xh[0][s], acc0);
      acc1 = MFMA16(a_h, xh[1][s], acc1);
      acc0 = MFMA16(a_l, xh[0][s], acc0);
      acc1 = MFMA16(a_l, xh[1][s], acc1);
    }

    const int codebase = h * 2048 + it * 32 + 4 * (l >> 5);
    update(acc0, 0, codebase);
    update(acc1, 1, codebase);
    __syncthreads();
  }

  // Merge lane pair (l, l^32): same x-row, complementary code rows.
#pragma unroll
  for (int tt = 0; tt < 2; ++tt) {
    float o1 = __shfl_xor(min1[tt], 32);
    float o2 = __shfl_xor(min2[tt], 32);
    int oi = __shfl_xor(idx[tt], 32);
    bool sw = (o1 < min1[tt]) || (o1 == min1[tt] && oi < idx[tt]);
    float n1 = sw ? o1 : min1[tt];
    int ni = sw ? oi : idx[tt];
    float big = sw ? min1[tt] : o1;
    float n2 = fminf(fminf(min2[tt], o2), big);
    if (l < 32) {
      int row = row0 + w * 64 + tt * 32 + l;
      pm1[h * Bn + row] = n1;
      pm2[h * Bn + row] = n2;
      pidx[h * Bn + row] = (float)ni;
    }
  }
}

// ---------------------------------------------------------------------------
// Merge the two code-half partials; write idxf; flag small-margin rows.
// (pm values live in key+512 space; margins are shift-invariant.)
// ---------------------------------------------------------------------------
__global__ void merge_kernel(const float* __restrict__ pm1,
                             const float* __restrict__ pm2,
                             const float* __restrict__ pidx,
                             float* __restrict__ idxf,
                             int* __restrict__ flaglist,
                             int* __restrict__ flagcount) {
  int r = blockIdx.x * 256 + threadIdx.x;
  float a1 = pm1[r], b1 = pm1[Bn + r];
  float a2 = pm2[r], b2 = pm2[Bn + r];
  float ai = pidx[r], bi = pidx[Bn + r];
  bool a = (a1 <= b1);
  float m1 = a ? a1 : b1;
  float mi = a ? ai : bi;
  float m2 = a ? fminf(a2, b1) : fminf(b2, a1);
  idxf[r] = mi;
  if (m2 - m1 < TAU) {
    int p = atomicAdd(flagcount, 1);
    flaglist[p] = r;
  }
}

// ---------------------------------------------------------------------------
// Exact fp32 rescore of flagged rows (grid-stride block-per-row, proven).
// ---------------------------------------------------------------------------
__global__ void rescore_kernel(const float* __restrict__ x,
                               const float* __restrict__ codes,
                               const float* __restrict__ cnorm,
                               const int* __restrict__ flaglist,
                               const int* __restrict__ flagcount,
                               float* __restrict__ idxf) {
  __shared__ __align__(16) float xrow[Dn];
  __shared__ float rv[256];
  __shared__ int ri[256];
  const int t = threadIdx.x;
  const int cnt = *flagcount;

  for (int j = blockIdx.x; j < cnt; j += gridDim.x) {
    const int r = flaglist[j];
    __syncthreads();
    if (t < 32) ((float4*)xrow)[t] = ((const float4*)(x + (size_t)r * Dn))[t];
    __syncthreads();
    float bv = 3.4e38f;
    int bi = 0x7fffffff;
    for (int c = t; c < Cn; c += 256) {
      const float4* cp = (const float4*)(codes + (size_t)c * Dn);
      float s = 0.f;
#pragma unroll
      for (int i = 0; i < Dn / 4; ++i) {
        float4 v = cp[i];
        float4 u = ((const float4*)xrow)[i];
        s = fmaf(v.x, u.x, s);
        s = fmaf(v.y, u.y, s);
        s = fmaf(v.z, u.z, s);
        s = fmaf(v.w, u.w, s);
      }
      float key = fmaf(-2.f, s, cnorm[c]);
      if (key < bv) { bv = key; bi = c; }
    }
    rv[t] = bv;
    ri[t] = bi;
    __syncthreads();
    for (int off = 128; off > 0; off >>= 1) {
      if (t < off) {
        float ov = rv[t + off];
        int oi = ri[t + off];
        if (ov < rv[t] || (ov == rv[t] && oi < ri[t])) {
          rv[t] = ov;
          ri[t] = oi;
        }
      }
      __syncthreads();
    }
    if (t == 0) idxf[r] = (float)ri[0];
  }
}

// ---------------------------------------------------------------------------
// Gather + per-block loss partial (no global atomics).
// ---------------------------------------------------------------------------
__global__ void gather_loss_kernel(const float* __restrict__ x,
                                   const float* __restrict__ codes,
                                   const float* __restrict__ idxf,
                                   float* __restrict__ quant,
                                   float* __restrict__ partial) {
  __shared__ float part[8];
  const int t = threadIdx.x;
  const int wave = t >> 6;
  const int lane = t & 63;
  const int half = lane >> 5;
  const int l = lane & 31;
  const int base = blockIdx.x * 32;

  float s = 0.f;
#pragma unroll
  for (int pass = 0; pass < 4; ++pass) {
    int row = base + pass * 8 + (wave << 1) + half;
    int idx = (int)idxf[row];
    float4 cv = ((const float4*)(codes + (size_t)idx * Dn))[l];
    float4 xv = ((const float4*)(x + (size_t)row * Dn))[l];
    ((float4*)(quant + (size_t)row * Dn))[l] = cv;
    float d0 = xv.x - cv.x, d1 = xv.y - cv.y, d2 = xv.z - cv.z,
          d3 = xv.w - cv.w;
    s += d0 * d0 + d1 * d1 + d2 * d2 + d3 * d3;
  }
#pragma unroll
  for (int off = 16; off > 0; off >>= 1) s += __shfl_down(s, off, 32);
  if (l == 0) part[(wave << 1) + half] = s;
  __syncthreads();
  if (t == 0) {
    float tot = 0.f;
#pragma unroll
    for (int i = 0; i < 8; ++i) tot += part[i];
    partial[blockIdx.x] = tot;
  }
}

// ---------------------------------------------------------------------------
// Final loss reduction: 2048 partials -> loss (direct write, no pre-zero).
// ---------------------------------------------------------------------------
__global__ void loss_sum_kernel(const float* __restrict__ partial,
                                float* __restrict__ loss) {
  __shared__ float red[4];
  const int t = threadIdx.x;
  float s = 0.f;
  for (int i = t; i < 2048; i += 256) s += partial[i];
#pragma unroll
  for (int off = 32; off > 0; off >>= 1) s += __shfl_down(s, off, 64);
  if ((t & 63) == 0) red[t >> 6] = s;
  __syncthreads();
  if (t == 0)
    *loss = (red[0] + red[1] + red[2] + red[3]) * (1.25f / 65536.f);
}

// ---------------------------------------------------------------------------
extern "C" void kernel_launch(void* const* d_in, const int* in_sizes, int n_in,
                              void* d_out, int out_size, void* d_ws,
                              size_t ws_size, hipStream_t stream) {
  const float* x = (const float*)d_in[0];
  const float* codes = (const float*)d_in[1];

  float* quant = (float*)d_out;            // B*D floats (scratch until gather)
  float* idxf = quant + (size_t)Bn * Dn;   // B floats
  float* loss = idxf + Bn;                 // 1 float
  float* cnorm = (float*)d_ws;             // 16 KB
  float* partial = cnorm + Cn;             // 8 KB

  _Float16* pack = (_Float16*)quant;           // 2.25 MB @ 0
  int* flagcount = (int*)(quant + (1 << 20));  // @ 4 MB
  int* flaglist = flagcount + 1;               // up to 256 KB
  float* pm1 = quant + (2 << 20);              // @ 8 MB
  float* pm2 = pm1 + 2 * Bn;
  float* pidx = pm2 + 2 * Bn;

  pack_codes_kernel<<<288, 256, 0, stream>>>(codes, cnorm, pack, flagcount);
  argmin_mfma_kernel<<<512, 256, 0, stream>>>(x, pack, pm1, pm2, pidx);
  merge_kernel<<<Bn / 256, 256, 0, stream>>>(pm1, pm2, pidx, idxf, flaglist,
                                             flagcount);
  rescore_kernel<<<512, 256, 0, stream>>>(x, codes, cnorm, flaglist, flagcount,
                                          idxf);
  gather_loss_kernel<<<Bn / 32, 256, 0, stream>>>(x, codes, idxf, quant,
                                                  partial);
  loss_sum_kernel<<<1, 256, 0, stream>>>(partial, loss);
}